// Round 3
// baseline (711.730 us; speedup 1.0000x reference)
//
#include <hip/hip_runtime.h>
#include <hip/hip_bf16.h>

#define S_LEN 2048
#define NEGF -1000000000.0f
#define QSC 0.18033688f  // 0.125 * log2(e)

typedef unsigned short ushort_t;
typedef __attribute__((ext_vector_type(8))) short short8;
typedef __attribute__((ext_vector_type(4))) float f32x4;

#if defined(__has_builtin)
#if __has_builtin(__builtin_amdgcn_exp2f)
#define EXP2 __builtin_amdgcn_exp2f
#endif
#endif
#ifndef EXP2
#define EXP2 exp2f
#endif

__device__ __forceinline__ unsigned short f2b(float f) {
  unsigned int u = __float_as_uint(f);
  return (unsigned short)((u + 0x7fffu + ((u >> 16) & 1u)) >> 16);
}

__device__ __forceinline__ void gld_lds16(const void* g, void* l) {
  __builtin_amdgcn_global_load_lds((__attribute__((address_space(1))) unsigned int*)g,
                                   (__attribute__((address_space(3))) unsigned int*)l, 16, 0, 0);
}

// ---------------- weight transpose f32[K,N] -> bf16[N,K] ----------------
__device__ __forceinline__ void wtrans_body(const float* __restrict__ W,
                                            ushort_t* __restrict__ Wt, int K, int N,
                                            int bx, int by) {
  __shared__ float t[32][33];
  int n0 = bx * 32, k0 = by * 32;
  int tx = threadIdx.x & 31, ty = threadIdx.x >> 5;
#pragma unroll
  for (int i = 0; i < 32; i += 8)
    t[ty + i][tx] = W[(size_t)(k0 + ty + i) * N + n0 + tx];
  __syncthreads();
#pragma unroll
  for (int i = 0; i < 32; i += 8)
    Wt[(size_t)(n0 + ty + i) * K + k0 + tx] = f2b(t[tx][ty + i]);
}

__global__ __launch_bounds__(256) void wtrans(const float* __restrict__ W,
                                              ushort_t* __restrict__ Wt, int K, int N) {
  wtrans_body(W, Wt, K, N, blockIdx.x, blockIdx.y);
}

struct P8 {
  const float* s[8];
  ushort_t* d[8];
};
__global__ __launch_bounds__(256) void wtrans8(P8 p) {
  wtrans_body(p.s[blockIdx.z], p.d[blockIdx.z], 1024, 1024, blockIdx.x, blockIdx.y);
}

__global__ __launch_bounds__(256) void f2bcvt(const float* __restrict__ in,
                                              ushort_t* __restrict__ out) {
  size_t i = ((size_t)blockIdx.x * 256 + threadIdx.x) * 4;
  float4 v = *(const float4*)(in + i);
  union { unsigned short u[4]; uint2 q; } pk;
  pk.u[0] = f2b(v.x); pk.u[1] = f2b(v.y); pk.u[2] = f2b(v.z); pk.u[3] = f2b(v.w);
  *(uint2*)(out + i) = pk.q;
}

__global__ __launch_bounds__(256) void bcat(float* __restrict__ dst, const float* __restrict__ a,
                                            const float* __restrict__ b,
                                            const float* __restrict__ c, int n0, int n1) {
  int i = blockIdx.x * 256 + threadIdx.x;
  float v = (i < n0) ? a[i] : (i < n0 + n1 ? b[i - n0] : c[i - n0 - n1]);
  dst[i] = v;
}

// pad masks -> global f32 (frees 8KB LDS in attention for K/V double-buffer)
__global__ __launch_bounds__(256) void padmask(const int* __restrict__ tids,
                                               const int* __restrict__ iids,
                                               float* __restrict__ pmA,
                                               float* __restrict__ pmB) {
  int i = blockIdx.x * 256 + threadIdx.x;
  pmA[i] = (tids[i] == 0) ? NEGF : 0.0f;
  pmB[i] = (iids[i] == 0) ? NEGF : 0.0f;
}

// ---------------- layernorm ----------------
__device__ __forceinline__ void row_stats(float s, float ss, float* outMean, float* outRstd) {
  __shared__ float red[8];
#pragma unroll
  for (int o = 32; o > 0; o >>= 1) {
    s += __shfl_down(s, o);
    ss += __shfl_down(ss, o);
  }
  int wave = threadIdx.x >> 6, lane = threadIdx.x & 63;
  if (lane == 0) { red[wave] = s; red[4 + wave] = ss; }
  __syncthreads();
  if (threadIdx.x == 0) {
    float S0 = red[0] + red[1] + red[2] + red[3];
    float S1 = red[4] + red[5] + red[6] + red[7];
    float mean = S0 * (1.0f / 1024.0f);
    float var = S1 * (1.0f / 1024.0f) - mean * mean;
    red[0] = mean;
    red[1] = rsqrtf(var + 1e-5f);
  }
  __syncthreads();
  *outMean = red[0];
  *outRstd = red[1];
}

__global__ __launch_bounds__(256) void embed_ln(const int* __restrict__ tids,
                                                const float* __restrict__ tok,
                                                const float* __restrict__ pos,
                                                const float* __restrict__ g,
                                                const float* __restrict__ be,
                                                float* __restrict__ xf,
                                                ushort_t* __restrict__ xb) {
  int row = blockIdx.x;
  int s = row & (S_LEN - 1);
  int id = tids[row];
  int c = threadIdx.x * 4;
  float4 v = *(const float4*)(tok + (size_t)id * 1024 + c);
  float4 p = *(const float4*)(pos + (size_t)s * 1024 + c);
  v.x += p.x; v.y += p.y; v.z += p.z; v.w += p.w;
  float mean, rstd;
  row_stats(v.x + v.y + v.z + v.w, v.x * v.x + v.y * v.y + v.z * v.z + v.w * v.w, &mean, &rstd);
  float4 gv = *(const float4*)(g + c);
  float4 bv = *(const float4*)(be + c);
  float4 o;
  o.x = (v.x - mean) * rstd * gv.x + bv.x;
  o.y = (v.y - mean) * rstd * gv.y + bv.y;
  o.z = (v.z - mean) * rstd * gv.z + bv.z;
  o.w = (v.w - mean) * rstd * gv.w + bv.w;
  *(float4*)(xf + (size_t)row * 1024 + c) = o;
  union { unsigned short u[4]; uint2 q; } pk;
  pk.u[0] = f2b(o.x); pk.u[1] = f2b(o.y); pk.u[2] = f2b(o.z); pk.u[3] = f2b(o.w);
  *(uint2*)(xb + (size_t)row * 1024 + c) = pk.q;
}

__global__ __launch_bounds__(256) void ln_fwd(const float* in, const float* __restrict__ g,
                                              const float* __restrict__ be, float* outF,
                                              ushort_t* __restrict__ outB) {
  int row = blockIdx.x;
  int c = threadIdx.x * 4;
  float4 v = *(const float4*)(in + (size_t)row * 1024 + c);
  float mean, rstd;
  row_stats(v.x + v.y + v.z + v.w, v.x * v.x + v.y * v.y + v.z * v.z + v.w * v.w, &mean, &rstd);
  float4 gv = *(const float4*)(g + c);
  float4 bv = *(const float4*)(be + c);
  float4 o;
  o.x = (v.x - mean) * rstd * gv.x + bv.x;
  o.y = (v.y - mean) * rstd * gv.y + bv.y;
  o.z = (v.z - mean) * rstd * gv.z + bv.z;
  o.w = (v.w - mean) * rstd * gv.w + bv.w;
  if (outF) *(float4*)(outF + (size_t)row * 1024 + c) = o;
  union { unsigned short u[4]; uint2 q; } pk;
  pk.u[0] = f2b(o.x); pk.u[1] = f2b(o.y); pk.u[2] = f2b(o.z); pk.u[3] = f2b(o.w);
  *(uint2*)(outB + (size_t)row * 1024 + c) = pk.q;
}

// ---------------- 128x128 bf16 MFMA GEMM (2-phase; 3 blk/CU grids) ----------------
__global__ __launch_bounds__(256) void gemm_bt(const ushort_t* __restrict__ A,
                                               const ushort_t* __restrict__ Bt,
                                               const float* __restrict__ bias,
                                               const float* __restrict__ res,
                                               float* __restrict__ outF,
                                               ushort_t* __restrict__ outB,
                                               ushort_t* __restrict__ outT,
                                               int M, int N, int K, int act, int scaleN,
                                               int nSplit) {
  __shared__ __align__(16) ushort_t lA[128 * 64];
  __shared__ __align__(16) ushort_t lB[128 * 64];
  const int tid = threadIdx.x;
  const int wave = tid >> 6, lane = tid & 63;
  const int quad = lane >> 4, l16 = lane & 15;
  const int m0 = blockIdx.y * 128, n0 = blockIdx.x * 128;
  const int wm = (wave >> 1) * 64, wn = (wave & 1) * 64;

  f32x4 zero4 = {0.f, 0.f, 0.f, 0.f};
  f32x4 acc[4][4];
#pragma unroll
  for (int i = 0; i < 4; ++i)
#pragma unroll
    for (int j = 0; j < 4; ++j) acc[i][j] = zero4;

  int rowS[4], chkS[4];
#pragma unroll
  for (int ii = 0; ii < 4; ++ii) {
    int d = (wave * 4 + ii) * 64 + lane;
    rowS[ii] = d >> 3;
    chkS[ii] = (d & 7) ^ (rowS[ii] & 7);
  }

  for (int kt = 0; kt < K; kt += 64) {
    __syncthreads();
#pragma unroll
    for (int ii = 0; ii < 4; ++ii) {
      gld_lds16(A + (size_t)(m0 + rowS[ii]) * K + kt + chkS[ii] * 8,
                (char*)lA + (wave * 4 + ii) * 1024);
      gld_lds16(Bt + (size_t)(n0 + rowS[ii]) * K + kt + chkS[ii] * 8,
                (char*)lB + (wave * 4 + ii) * 1024);
    }
    __syncthreads();
#pragma unroll
    for (int kc = 0; kc < 2; ++kc) {
      short8 af[4], bf[4];
#pragma unroll
      for (int mt = 0; mt < 4; ++mt) {
        int r = wm + mt * 16 + l16;
        int c = (kc * 4 + quad) ^ (r & 7);
        af[mt] = *(const short8*)(lA + r * 64 + c * 8);
      }
#pragma unroll
      for (int nt = 0; nt < 4; ++nt) {
        int r = wn + nt * 16 + l16;
        int c = (kc * 4 + quad) ^ (r & 7);
        bf[nt] = *(const short8*)(lB + r * 64 + c * 8);
      }
#pragma unroll
      for (int mt = 0; mt < 4; ++mt)
#pragma unroll
        for (int nt = 0; nt < 4; ++nt)
          acc[mt][nt] = __builtin_amdgcn_mfma_f32_16x16x32_bf16(af[mt], bf[nt], acc[mt][nt], 0, 0, 0);
    }
  }

#pragma unroll
  for (int nt = 0; nt < 4; ++nt) {
    int gn = n0 + wn + nt * 16 + l16;
    float bv = bias[gn];
    if (gn < nSplit) {
#pragma unroll
      for (int mt = 0; mt < 4; ++mt) {
        int gmb = m0 + wm + mt * 16 + quad * 4;
#pragma unroll
        for (int reg = 0; reg < 4; ++reg) {
          size_t idx = (size_t)(gmb + reg) * nSplit + gn;
          float v = acc[mt][nt][reg] + bv;
          if (act == 1) v = 0.5f * v * (1.0f + erff(v * 0.70710678118654752f));
          if (gn < scaleN) v *= QSC;
          if (res) v += res[idx];
          if (outF) outF[idx] = v;
          if (outB) outB[idx] = f2b(v);
        }
      }
    } else {
#pragma unroll
      for (int mt = 0; mt < 4; ++mt) {
        int gmb = m0 + wm + mt * 16 + quad * 4;
        union { unsigned short u[4]; uint2 q; } pk;
#pragma unroll
        for (int reg = 0; reg < 4; ++reg) pk.u[reg] = f2b(acc[mt][nt][reg] + bv);
        *(uint2*)(outT + (size_t)(gn - nSplit) * M + gmb) = pk.q;
      }
    }
  }
}

// ---------------- 256x256 8-phase bf16 MFMA GEMM, counted vmcnt ----------------
// 8 waves (2M x 4N), BK=64, 128KiB double-buffered LDS (1 blk/CU), grid must be
// >= 256 blocks. Per phase q (one C-quadrant x K=64): 12 ds_read_b128 -> stage
// ONE half-tile of tile t+1 (q0->A0,q1->B0,q2->B1,q3->A1; 2 loads/thread) ->
// s_barrier -> lgkmcnt(0) -> setprio(1)+16 MFMA+setprio(0) -> vmcnt(4) ->
// s_barrier. FIFO proof: at each phase-end wait, the half-tiles the NEXT phase
// reads are older than the 4 permitted outstanding loads; wait precedes a
// barrier, consuming ds_reads follow it, phases are barrier-lockstep, so
// per-wave vmcnt gives block-wide visibility. Never drains to 0 mid-loop.
__global__ __launch_bounds__(512, 2) void gemm256(const ushort_t* __restrict__ A,
                                                  const ushort_t* __restrict__ Bt,
                                                  const float* __restrict__ bias,
                                                  const float* __restrict__ res,
                                                  float* __restrict__ outF,
                                                  ushort_t* __restrict__ outB,
                                                  ushort_t* __restrict__ outT,
                                                  int M, int N, int K, int act, int scaleN,
                                                  int nSplit) {
  __shared__ __align__(16) ushort_t sA[2][256 * 64];
  __shared__ __align__(16) ushort_t sB[2][256 * 64];
  const int tid = threadIdx.x;
  const int wave = tid >> 6, lane = tid & 63;
  const int quad = lane >> 4, l16 = lane & 15;
  const int m0 = blockIdx.y * 256, n0 = blockIdx.x * 256;
  const int wm = (wave >> 2) * 128, wn = (wave & 3) * 64;

  const ushort_t* Ab = A + (size_t)m0 * K;
  const ushort_t* Bb = Bt + (size_t)n0 * K;

  const int srow = tid >> 3;                        // 0..63
  const int schk = ((tid & 7) ^ (srow & 7)) << 3;   // swizzled element offset in row

#define STAGE_H(SRC, LD, KT, DST, H)                                          \
  do {                                                                        \
    gld_lds16((SRC) + (size_t)((H) * 128 + srow) * (LD) + (KT) + schk,        \
              (char*)(DST) + (H) * 16384 + tid * 16);                         \
    gld_lds16((SRC) + (size_t)((H) * 128 + 64 + srow) * (LD) + (KT) + schk,   \
              (char*)(DST) + (H) * 16384 + 8192 + tid * 16);                  \
  } while (0)

  f32x4 zero4 = {0.f, 0.f, 0.f, 0.f};
  f32x4 acc[8][4];
#pragma unroll
  for (int i = 0; i < 8; ++i)
#pragma unroll
    for (int j = 0; j < 4; ++j) acc[i][j] = zero4;

  const int NT = K >> 6;

  // prologue: stage tile 0 half-tiles in deadline order A0,B0,B1,A1
  STAGE_H(Ab, K, 0, sA[0], 0);
  STAGE_H(Bb, K, 0, sB[0], 0);
  STAGE_H(Bb, K, 0, sB[0], 1);
  STAGE_H(Ab, K, 0, sA[0], 1);
  asm volatile("s_waitcnt vmcnt(4)" ::: "memory");
  __builtin_amdgcn_s_barrier();

  for (int t = 0; t < NT; ++t) {
    const ushort_t* curA = sA[t & 1];
    const ushort_t* curB = sB[t & 1];
    ushort_t* nxtA = sA[(t + 1) & 1];
    ushort_t* nxtB = sB[(t + 1) & 1];
    const int ktn = (t + 1) << 6;
    const bool more = (t + 1 < NT);
#pragma unroll
    for (int q = 0; q < 4; ++q) {
      const int mh = q >> 1, nh = q & 1;
      short8 af[4][2], bf[2][2];
#pragma unroll
      for (int mt = 0; mt < 4; ++mt)
#pragma unroll
        for (int kc = 0; kc < 2; ++kc) {
          int r = wm + (mh * 4 + mt) * 16 + l16;
          af[mt][kc] = *(const short8*)(curA + r * 64 + (((kc * 4 + quad) ^ (r & 7)) << 3));
        }
#pragma unroll
      for (int nt = 0; nt < 2; ++nt)
#pragma unroll
        for (int kc = 0; kc < 2; ++kc) {
          int r = wn + (nh * 2 + nt) * 16 + l16;
          bf[nt][kc] = *(const short8*)(curB + r * 64 + (((kc * 4 + quad) ^ (r & 7)) << 3));
        }
      if (more) {
        if (q == 0) STAGE_H(Ab, K, ktn, nxtA, 0);
        else if (q == 1) STAGE_H(Bb, K, ktn, nxtB, 0);
        else if (q == 2) STAGE_H(Bb, K, ktn, nxtB, 1);
        else STAGE_H(Ab, K, ktn, nxtA, 1);
      }
      __builtin_amdgcn_s_barrier();
      asm volatile("s_waitcnt lgkmcnt(0)" ::: "memory");
      __builtin_amdgcn_s_setprio(1);
#pragma unroll
      for (int mt = 0; mt < 4; ++mt)
#pragma unroll
        for (int nt = 0; nt < 2; ++nt)
#pragma unroll
          for (int kc = 0; kc < 2; ++kc)
            acc[mh * 4 + mt][nh * 2 + nt] = __builtin_amdgcn_mfma_f32_16x16x32_bf16(
                af[mt][kc], bf[nt][kc], acc[mh * 4 + mt][nh * 2 + nt], 0, 0, 0);
      __builtin_amdgcn_s_setprio(0);
      if (more) asm volatile("s_waitcnt vmcnt(4)" ::: "memory");
      else asm volatile("s_waitcnt vmcnt(0)" ::: "memory");
      __builtin_amdgcn_s_barrier();
    }
  }
#undef STAGE_H

#pragma unroll
  for (int nt = 0; nt < 4; ++nt) {
    int gn = n0 + wn + nt * 16 + l16;
    float bv = bias[gn];
    if (gn < nSplit) {
#pragma unroll
      for (int mt = 0; mt < 8; ++mt) {
        int gmb = m0 + wm + mt * 16 + quad * 4;
#pragma unroll
        for (int reg = 0; reg < 4; ++reg) {
          size_t idx = (size_t)(gmb + reg) * nSplit + gn;
          float v = acc[mt][nt][reg] + bv;
          if (act == 1) v = 0.5f * v * (1.0f + erff(v * 0.70710678118654752f));
          if (gn < scaleN) v *= QSC;
          if (res) v += res[idx];
          if (outF) outF[idx] = v;
          if (outB) outB[idx] = f2b(v);
        }
      }
    } else {
#pragma unroll
      for (int mt = 0; mt < 8; ++mt) {
        int gmb = m0 + wm + mt * 16 + quad * 4;
        union { unsigned short u[4]; uint2 q2; } pk;
#pragma unroll
        for (int reg = 0; reg < 4; ++reg) pk.u[reg] = f2b(acc[mt][nt][reg] + bv);
        *(uint2*)(outT + (size_t)(gn - nSplit) * M + gmb) = pk.q2;
      }
    }
  }
}

// ---------------- 128x64 tile GEMM, prefetch double-buffer ----------------
__global__ __launch_bounds__(256) void gemm_n64(const ushort_t* __restrict__ A,
                                                const ushort_t* __restrict__ Bt,
                                                const float* __restrict__ bias,
                                                const float* __restrict__ res,
                                                float* __restrict__ outF,
                                                ushort_t* __restrict__ outB,
                                                int M, int N, int K, int act, int scaleN) {
  __shared__ __align__(16) ushort_t lA[2][128 * 64];
  __shared__ __align__(16) ushort_t lB[2][64 * 64];
  const int tid = threadIdx.x;
  const int wave = tid >> 6, lane = tid & 63;
  const int quad = lane >> 4, l16 = lane & 15;
  const int m0 = blockIdx.y * 128, n0 = blockIdx.x * 64;
  const int wm = wave * 32;

  f32x4 zero4 = {0.f, 0.f, 0.f, 0.f};
  f32x4 acc[2][4];
#pragma unroll
  for (int i = 0; i < 2; ++i)
#pragma unroll
    for (int j = 0; j < 4; ++j) acc[i][j] = zero4;

  int rowA[4], chkA[4], rowB[2], chkB[2];
#pragma unroll
  for (int ii = 0; ii < 4; ++ii) {
    int d = (wave * 4 + ii) * 64 + lane;
    rowA[ii] = d >> 3;
    chkA[ii] = (d & 7) ^ (rowA[ii] & 7);
  }
#pragma unroll
  for (int ii = 0; ii < 2; ++ii) {
    int d = (wave * 2 + ii) * 64 + lane;
    rowB[ii] = d >> 3;
    chkB[ii] = (d & 7) ^ (rowB[ii] & 7);
  }

#define STG64(KT, BUF)                                                         \
  do {                                                                         \
    _Pragma("unroll") for (int ii = 0; ii < 4; ++ii)                           \
        gld_lds16(A + (size_t)(m0 + rowA[ii]) * K + (KT) + chkA[ii] * 8,       \
                  (char*)lA[BUF] + (wave * 4 + ii) * 1024);                    \
    _Pragma("unroll") for (int ii = 0; ii < 2; ++ii)                           \
        gld_lds16(Bt + (size_t)(n0 + rowB[ii]) * K + (KT) + chkB[ii] * 8,      \
                  (char*)lB[BUF] + (wave * 2 + ii) * 1024);                    \
  } while (0)

  STG64(0, 0);
  __syncthreads();

  int cur = 0;
  for (int kt = 0; kt < K; kt += 64) {
    if (kt + 64 < K) STG64(kt + 64, cur ^ 1);
    const ushort_t* cA = lA[cur];
    const ushort_t* cB = lB[cur];
#pragma unroll
    for (int kc = 0; kc < 2; ++kc) {
      short8 af[2], bf[4];
#pragma unroll
      for (int mt = 0; mt < 2; ++mt) {
        int r = wm + mt * 16 + l16;
        int c = (kc * 4 + quad) ^ (r & 7);
        af[mt] = *(const short8*)(cA + r * 64 + c * 8);
      }
#pragma unroll
      for (int nt = 0; nt < 4; ++nt) {
        int r = nt * 16 + l16;
        int c = (kc * 4 + quad) ^ (r & 7);
        bf[nt] = *(const short8*)(cB + r * 64 + c * 8);
      }
#pragma unroll
      for (int mt = 0; mt < 2; ++mt)
#pragma unroll
        for (int nt = 0; nt < 4; ++nt)
          acc[mt][nt] = __builtin_amdgcn_mfma_f32_16x16x32_bf16(af[mt], bf[nt], acc[mt][nt], 0, 0, 0);
    }
    __syncthreads();
    cur ^= 1;
  }
#undef STG64

#pragma unroll
  for (int nt = 0; nt < 4; ++nt) {
    int gn = n0 + nt * 16 + l16;
    float bv = bias[gn];
#pragma unroll
    for (int mt = 0; mt < 2; ++mt) {
      int gmb = m0 + wm + mt * 16 + quad * 4;
#pragma unroll
      for (int reg = 0; reg < 4; ++reg) {
        size_t idx = (size_t)(gmb + reg) * N + gn;
        float v = acc[mt][nt][reg] + bv;
        if (act == 1) v = 0.5f * v * (1.0f + erff(v * 0.70710678118654752f));
        if (gn < scaleN) v *= QSC;
        if (res) v += res[idx];
        if (outF) outF[idx] = v;
        if (outB) outB[idx] = f2b(v);
      }
    }
  }
}

// ---------------- flash attention v4: prefetch double-buffered K/V ----------------
template <int CAUSAL>
__global__ __launch_bounds__(256, 4) void attn4(const ushort_t* __restrict__ Qp, int ldQ,
                                                const ushort_t* __restrict__ Kp, int ldK,
                                                const ushort_t* __restrict__ Vt,
                                                const float* __restrict__ pmg,
                                                ushort_t* __restrict__ O) {
  __shared__ __align__(16) ushort_t lK[2][64 * 64];
  __shared__ __align__(16) ushort_t lV[2][64 * 64];
  __shared__ __align__(16) ushort_t lP[4][16 * 64];

  const int h = blockIdx.y, b = blockIdx.z;
  const int g = CAUSAL ? (31 - (int)blockIdx.x) : (int)blockIdx.x;  // heavy blocks first
  const int tid = threadIdx.x;
  const int wave = tid >> 6, lane = tid & 63;
  const int quad = lane >> 4, l16 = lane & 15;
  const int g0 = g * 64;
  const float* pmb = pmg + b * S_LEN;

  const int qrow = g0 + wave * 16 + l16;
  const ushort_t* qb = Qp + ((size_t)(b * S_LEN) + qrow) * ldQ + h * 64;
  short8 qf[2];
  qf[0] = *(const short8*)(qb + quad * 8);
  qf[1] = *(const short8*)(qb + 32 + quad * 8);

  f32x4 zero4 = {0.f, 0.f, 0.f, 0.f};
  f32x4 acc_o[4];
#pragma unroll
  for (int nt = 0; nt < 4; ++nt) acc_o[nt] = zero4;
  float lsum[4] = {0.f, 0.f, 0.f, 0.f};

  const int nkv = CAUSAL ? (g + 1) : (S_LEN / 64);
  const int qbase = g0 + wave * 16 + quad * 4;

  int srow[2], scs[2];
#pragma unroll
  for (int ii = 0; ii < 2; ++ii) {
    int slot = (wave * 2 + ii) * 64 + lane;
    srow[ii] = slot >> 3;
    scs[ii] = ((slot & 7) ^ (srow[ii] & 7)) * 8;
  }

#define STAGE_KV(KV0, BUF)                                                            \
  do {                                                                                \
    _Pragma("unroll") for (int ii = 0; ii < 2; ++ii) {                                \
      gld_lds16(Kp + (size_t)(b * S_LEN + (KV0) + srow[ii]) * ldK + h * 64 + scs[ii], \
                (char*)lK[BUF] + (wave * 2 + ii) * 1024);                             \
      gld_lds16(Vt + (size_t)(h * 64 + srow[ii]) * 4096 + b * S_LEN + (KV0) + scs[ii],\
                (char*)lV[BUF] + (wave * 2 + ii) * 1024);                             \
    }                                                                                 \
  } while (0)

  STAGE_KV(0, 0);
  __syncthreads();

  int cur = 0;
  for (int kv = 0; kv < nkv; ++kv) {
    const int kv0 = kv * 64;
    if (kv + 1 < nkv) STAGE_KV(kv0 + 64, cur ^ 1);

    float pmv[4];
#pragma unroll
    for (int nt = 0; nt < 4; ++nt) pmv[nt] = pmb[kv0 + nt * 16 + l16];

    const ushort_t* cK = lK[cur];
    const ushort_t* cV = lV[cur];

    // S = Q K^T
    f32x4 sacc[4];
#pragma unroll
    for (int nt = 0; nt < 4; ++nt) sacc[nt] = zero4;
#pragma unroll
    for (int kc = 0; kc < 2; ++kc) {
#pragma unroll
      for (int nt = 0; nt < 4; ++nt) {
        int r = nt * 16 + l16;
        int c = (kc * 4 + quad) ^ (r & 7);
        short8 kf = *(const short8*)(cK + r * 64 + c * 8);
        sacc[nt] = __builtin_amdgcn_mfma_f32_16x16x32_bf16(qf[kc], kf, sacc[nt], 0, 0, 0);
      }
    }

    const bool diag = CAUSAL && (kv == g);
#pragma unroll
    for (int nt = 0; nt < 4; ++nt) {
      int kk = kv0 + nt * 16 + l16;
#pragma unroll
      for (int reg = 0; reg < 4; ++reg) {
        float s = sacc[nt][reg] + pmv[nt];
        if (diag && kk > qbase + reg) s = NEGF;
        float p = EXP2(s);
        lsum[reg] += p;
        int q = quad * 4 + reg;
        int cc = (nt * 2 + (l16 >> 3)) ^ (q & 7);
        lP[wave][q * 64 + cc * 8 + (l16 & 7)] = f2b(p);
      }
    }

    // O += P V
#pragma unroll
    for (int kc = 0; kc < 2; ++kc) {
      int cp = (kc * 4 + quad) ^ (l16 & 7);
      short8 pf = *(const short8*)(&lP[wave][l16 * 64 + cp * 8]);
#pragma unroll
      for (int nt = 0; nt < 4; ++nt) {
        int r = nt * 16 + l16;
        int c = (kc * 4 + quad) ^ (r & 7);
        short8 vf = *(const short8*)(cV + r * 64 + c * 8);
        acc_o[nt] = __builtin_amdgcn_mfma_f32_16x16x32_bf16(pf, vf, acc_o[nt], 0, 0, 0);
      }
    }
    __syncthreads();
    cur ^= 1;
  }  // kv
#undef STAGE_KV

  float inv[4];
#pragma unroll
  for (int reg = 0; reg < 4; ++reg) {
    float t = lsum[reg];
    t += __shfl_xor(t, 1);
    t += __shfl_xor(t, 2);
    t += __shfl_xor(t, 4);
    t += __shfl_xor(t, 8);
    inv[reg] = 1.0f / t;
  }
#pragma unroll
  for (int nt = 0; nt < 4; ++nt)
#pragma unroll
    for (int reg = 0; reg < 4; ++reg) {
      int qr = g0 + wave * 16 + quad * 4 + reg;
      O[((size_t)(b * S_LEN) + qr) * 1024 + h * 64 + nt * 16 + l16] =
          f2b(acc_o[nt][reg] * inv[reg]);
    }
}

// ---------------- launch ----------------
extern "C" void kernel_launch(void* const* d_in, const int* in_sizes, int n_in,
                              void* d_out, int out_size, void* d_ws, size_t ws_size,
                              hipStream_t stream) {
  (void)in_sizes; (void)n_in; (void)out_size; (void)ws_size;
  const size_t MB = 1024 * 1024;
  char* w = (char*)d_ws;
  ushort_t* qkv1T = (ushort_t*)(w + 0);        // [3072][1024] bf16, 6MB
  ushort_t* o1T = (ushort_t*)(w + 6 * MB);     // 2MB
  ushort_t* q2T = (ushort_t*)(w + 8 * MB);     // 2MB
  ushort_t* k2v2T = (ushort_t*)(w + 10 * MB);  // [2048][1024], 4MB
  ushort_t* o2T = (ushort_t*)(w + 14 * MB);    // 2MB
  ushort_t* m1T = (ushort_t*)(w + 16 * MB);    // [4096][1024], 8MB
  ushort_t* m2T = (ushort_t*)(w + 24 * MB);    // [1024][4096], 8MB
  float* bias3 = (float*)(w + 32 * MB);        // 12KB
  float* bias2 = (float*)(w + 32 * MB + 64 * 1024);
  float* pmA = (float*)(w + 32 * MB + 128 * 1024);  // 16KB causal/self pad mask
  float* pmB = (float*)(w + 32 * MB + 160 * 1024);  // 16KB cross pad mask
  ushort_t* xb = (ushort_t*)(w + 33 * MB);     // 8MB; reused later as hlnb
  ushort_t* QKb = (ushort_t*)(w + 41 * MB);    // [4096][2048], 16MB; later Q2b+K2b
  ushort_t* Vt = (ushort_t*)(w + 57 * MB);     // [1024][4096], 8MB (self then cross)
  ushort_t* Ob = (ushort_t*)(w + 65 * MB);     // 8MB
  ushort_t* encb = (ushort_t*)(w + 73 * MB);   // 8MB
  float* xf = (float*)(w + 81 * MB);           // 16MB (post-LN1 x; later r)
  float* hf = (float*)(w + 97 * MB);           // 16MB (x+attn; LN2 in place)
  ushort_t* m1b = (ushort_t*)(w + 113 * MB);   // 32MB
  ushort_t* hlnb = xb;
  ushort_t* Q2b = QKb;                  // [4096][1024]
  ushort_t* K2b = QKb + 4 * MB;         // +8MB bytes -> [4096][1024]

  dim3 B256(256);
  dim3 B512(512);
  // weight conversions
  P8 p8;
  p8.s[0] = (const float*)d_in[7];  p8.d[0] = qkv1T;
  p8.s[1] = (const float*)d_in[9];  p8.d[1] = qkv1T + 1024 * 1024;
  p8.s[2] = (const float*)d_in[11]; p8.d[2] = qkv1T + 2 * 1024 * 1024;
  p8.s[3] = (const float*)d_in[13]; p8.d[3] = o1T;
  p8.s[4] = (const float*)d_in[17]; p8.d[4] = q2T;
  p8.s[5] = (const float*)d_in[19]; p8.d[5] = k2v2T;
  p8.s[6] = (const float*)d_in[21]; p8.d[6] = k2v2T + 1024 * 1024;
  p8.s[7] = (const float*)d_in[23]; p8.d[7] = o2T;
  wtrans8<<<dim3(32, 32, 8), B256, 0, stream>>>(p8);
  wtrans<<<dim3(128, 32), B256, 0, stream>>>((const float*)d_in[27], m1T, 1024, 4096);
  wtrans<<<dim3(32, 128), B256, 0, stream>>>((const float*)d_in[29], m2T, 4096, 1024);
  f2bcvt<<<4096, B256, 0, stream>>>((const float*)d_in[0], encb);
  bcat<<<12, B256, 0, stream>>>(bias3, (const float*)d_in[8], (const float*)d_in[10],
                                (const float*)d_in[12], 1024, 1024);
  bcat<<<8, B256, 0, stream>>>(bias2, (const float*)d_in[20], (const float*)d_in[22],
                               (const float*)d_in[22], 1024, 1024);
  padmask<<<16, B256, 0, stream>>>((const int*)d_in[2], (const int*)d_in[1], pmA, pmB);

  // embed + LN1
  embed_ln<<<4096, B256, 0, stream>>>((const int*)d_in[2], (const float*)d_in[3],
                                      (const float*)d_in[4], (const float*)d_in[5],
                                      (const float*)d_in[6], xf, xb);
  // fused QKV1 (Q cols scaled, V cols transposed) - 128x128 (grid 768 = 3 blk/CU)
  gemm_bt<<<dim3(24, 32), B256, 0, stream>>>(xb, qkv1T, bias3, nullptr, nullptr, QKb, Vt,
                                             4096, 3072, 1024, 0, 1024, 2048);
  attn4<1><<<dim3(32, 16, 2), B256, 0, stream>>>(QKb, 2048, QKb + 1024, 2048, Vt, pmA, Ob);
  gemm_n64<<<dim3(16, 32), B256, 0, stream>>>(Ob, o1T, (const float*)d_in[14], xf, hf, nullptr,
                                              4096, 1024, 1024, 0, 0);
  ln_fwd<<<4096, B256, 0, stream>>>(hf, (const float*)d_in[15], (const float*)d_in[16], hf, hlnb);
  // cross-attn projections
  gemm_n64<<<dim3(16, 32), B256, 0, stream>>>(hlnb, q2T, (const float*)d_in[18], nullptr, nullptr,
                                              Q2b, 4096, 1024, 1024, 0, 1024);
  gemm_bt<<<dim3(16, 32), B256, 0, stream>>>(encb, k2v2T, bias2, nullptr, nullptr, K2b, Vt,
                                             4096, 2048, 1024, 0, 0, 1024);
  attn4<0><<<dim3(32, 16, 2), B256, 0, stream>>>(Q2b, 1024, K2b, 1024, Vt, pmB, Ob);
  gemm_n64<<<dim3(16, 32), B256, 0, stream>>>(Ob, o2T, (const float*)d_in[24], hf, xf, nullptr,
                                              4096, 1024, 1024, 0, 0);
  ln_fwd<<<4096, B256, 0, stream>>>(xf, (const float*)d_in[25], (const float*)d_in[26], nullptr,
                                    hlnb);
  // MLP
  gemm256<<<dim3(16, 16), B512, 0, stream>>>(hlnb, m1T, (const float*)d_in[28], nullptr, nullptr,
                                             m1b, nullptr, 4096, 4096, 1024, 1, 0, 4096);
  gemm_n64<<<dim3(16, 32), B256, 0, stream>>>(m1b, m2T, (const float*)d_in[30], xf, (float*)d_out,
                                              nullptr, 4096, 1024, 4096, 0, 0);
}

// Round 4
// 708.536 us; speedup vs baseline: 1.0045x; 1.0045x over previous
//
#include <hip/hip_runtime.h>
#include <hip/hip_bf16.h>

#define S_LEN 2048
#define NEGF -1000000000.0f
#define QSC 0.18033688f  // 0.125 * log2(e)

typedef unsigned short ushort_t;
typedef __attribute__((ext_vector_type(8))) short short8;
typedef __attribute__((ext_vector_type(4))) float f32x4;

#if defined(__has_builtin)
#if __has_builtin(__builtin_amdgcn_exp2f)
#define EXP2 __builtin_amdgcn_exp2f
#endif
#endif
#ifndef EXP2
#define EXP2 exp2f
#endif

__device__ __forceinline__ unsigned short f2b(float f) {
  unsigned int u = __float_as_uint(f);
  return (unsigned short)((u + 0x7fffu + ((u >> 16) & 1u)) >> 16);
}

__device__ __forceinline__ void gld_lds16(const void* g, void* l) {
  __builtin_amdgcn_global_load_lds((__attribute__((address_space(1))) unsigned int*)g,
                                   (__attribute__((address_space(3))) unsigned int*)l, 16, 0, 0);
}

// ---------------- weight transpose f32[K,N] -> bf16[N,K] ----------------
__device__ __forceinline__ void wtrans_body(const float* __restrict__ W,
                                            ushort_t* __restrict__ Wt, int K, int N,
                                            int bx, int by) {
  __shared__ float t[32][33];
  int n0 = bx * 32, k0 = by * 32;
  int tx = threadIdx.x & 31, ty = threadIdx.x >> 5;
#pragma unroll
  for (int i = 0; i < 32; i += 8)
    t[ty + i][tx] = W[(size_t)(k0 + ty + i) * N + n0 + tx];
  __syncthreads();
#pragma unroll
  for (int i = 0; i < 32; i += 8)
    Wt[(size_t)(n0 + ty + i) * K + k0 + tx] = f2b(t[tx][ty + i]);
}

__global__ __launch_bounds__(256) void wtrans(const float* __restrict__ W,
                                              ushort_t* __restrict__ Wt, int K, int N) {
  wtrans_body(W, Wt, K, N, blockIdx.x, blockIdx.y);
}

struct P8 {
  const float* s[8];
  ushort_t* d[8];
};
__global__ __launch_bounds__(256) void wtrans8(P8 p) {
  wtrans_body(p.s[blockIdx.z], p.d[blockIdx.z], 1024, 1024, blockIdx.x, blockIdx.y);
}

__global__ __launch_bounds__(256) void f2bcvt(const float* __restrict__ in,
                                              ushort_t* __restrict__ out) {
  size_t i = ((size_t)blockIdx.x * 256 + threadIdx.x) * 4;
  float4 v = *(const float4*)(in + i);
  union { unsigned short u[4]; uint2 q; } pk;
  pk.u[0] = f2b(v.x); pk.u[1] = f2b(v.y); pk.u[2] = f2b(v.z); pk.u[3] = f2b(v.w);
  *(uint2*)(out + i) = pk.q;
}

__global__ __launch_bounds__(256) void bcat(float* __restrict__ dst, const float* __restrict__ a,
                                            const float* __restrict__ b,
                                            const float* __restrict__ c, int n0, int n1) {
  int i = blockIdx.x * 256 + threadIdx.x;
  float v = (i < n0) ? a[i] : (i < n0 + n1 ? b[i - n0] : c[i - n0 - n1]);
  dst[i] = v;
}

// pad masks -> global f32
__global__ __launch_bounds__(256) void padmask(const int* __restrict__ tids,
                                               const int* __restrict__ iids,
                                               float* __restrict__ pmA,
                                               float* __restrict__ pmB) {
  int i = blockIdx.x * 256 + threadIdx.x;
  pmA[i] = (tids[i] == 0) ? NEGF : 0.0f;
  pmB[i] = (iids[i] == 0) ? NEGF : 0.0f;
}

// ---------------- layernorm ----------------
__device__ __forceinline__ void row_stats(float s, float ss, float* outMean, float* outRstd) {
  __shared__ float red[8];
#pragma unroll
  for (int o = 32; o > 0; o >>= 1) {
    s += __shfl_down(s, o);
    ss += __shfl_down(ss, o);
  }
  int wave = threadIdx.x >> 6, lane = threadIdx.x & 63;
  if (lane == 0) { red[wave] = s; red[4 + wave] = ss; }
  __syncthreads();
  if (threadIdx.x == 0) {
    float S0 = red[0] + red[1] + red[2] + red[3];
    float S1 = red[4] + red[5] + red[6] + red[7];
    float mean = S0 * (1.0f / 1024.0f);
    float var = S1 * (1.0f / 1024.0f) - mean * mean;
    red[0] = mean;
    red[1] = rsqrtf(var + 1e-5f);
  }
  __syncthreads();
  *outMean = red[0];
  *outRstd = red[1];
}

__global__ __launch_bounds__(256) void embed_ln(const int* __restrict__ tids,
                                                const float* __restrict__ tok,
                                                const float* __restrict__ pos,
                                                const float* __restrict__ g,
                                                const float* __restrict__ be,
                                                float* __restrict__ xf,
                                                ushort_t* __restrict__ xb) {
  int row = blockIdx.x;
  int s = row & (S_LEN - 1);
  int id = tids[row];
  int c = threadIdx.x * 4;
  float4 v = *(const float4*)(tok + (size_t)id * 1024 + c);
  float4 p = *(const float4*)(pos + (size_t)s * 1024 + c);
  v.x += p.x; v.y += p.y; v.z += p.z; v.w += p.w;
  float mean, rstd;
  row_stats(v.x + v.y + v.z + v.w, v.x * v.x + v.y * v.y + v.z * v.z + v.w * v.w, &mean, &rstd);
  float4 gv = *(const float4*)(g + c);
  float4 bv = *(const float4*)(be + c);
  float4 o;
  o.x = (v.x - mean) * rstd * gv.x + bv.x;
  o.y = (v.y - mean) * rstd * gv.y + bv.y;
  o.z = (v.z - mean) * rstd * gv.z + bv.z;
  o.w = (v.w - mean) * rstd * gv.w + bv.w;
  *(float4*)(xf + (size_t)row * 1024 + c) = o;
  union { unsigned short u[4]; uint2 q; } pk;
  pk.u[0] = f2b(o.x); pk.u[1] = f2b(o.y); pk.u[2] = f2b(o.z); pk.u[3] = f2b(o.w);
  *(uint2*)(xb + (size_t)row * 1024 + c) = pk.q;
}

__global__ __launch_bounds__(256) void ln_fwd(const float* in, const float* __restrict__ g,
                                              const float* __restrict__ be, float* outF,
                                              ushort_t* __restrict__ outB) {
  int row = blockIdx.x;
  int c = threadIdx.x * 4;
  float4 v = *(const float4*)(in + (size_t)row * 1024 + c);
  float mean, rstd;
  row_stats(v.x + v.y + v.z + v.w, v.x * v.x + v.y * v.y + v.z * v.z + v.w * v.w, &mean, &rstd);
  float4 gv = *(const float4*)(g + c);
  float4 bv = *(const float4*)(be + c);
  float4 o;
  o.x = (v.x - mean) * rstd * gv.x + bv.x;
  o.y = (v.y - mean) * rstd * gv.y + bv.y;
  o.z = (v.z - mean) * rstd * gv.z + bv.z;
  o.w = (v.w - mean) * rstd * gv.w + bv.w;
  if (outF) *(float4*)(outF + (size_t)row * 1024 + c) = o;
  union { unsigned short u[4]; uint2 q; } pk;
  pk.u[0] = f2b(o.x); pk.u[1] = f2b(o.y); pk.u[2] = f2b(o.z); pk.u[3] = f2b(o.w);
  *(uint2*)(outB + (size_t)row * 1024 + c) = pk.q;
}

// ---------------- 128x128 bf16 MFMA GEMM (2-phase) ----------------
__global__ __launch_bounds__(256) void gemm_bt(const ushort_t* __restrict__ A,
                                               const ushort_t* __restrict__ Bt,
                                               const float* __restrict__ bias,
                                               const float* __restrict__ res,
                                               float* __restrict__ outF,
                                               ushort_t* __restrict__ outB,
                                               ushort_t* __restrict__ outT,
                                               int M, int N, int K, int act, int scaleN,
                                               int nSplit) {
  __shared__ __align__(16) ushort_t lA[128 * 64];
  __shared__ __align__(16) ushort_t lB[128 * 64];
  const int tid = threadIdx.x;
  const int wave = tid >> 6, lane = tid & 63;
  const int quad = lane >> 4, l16 = lane & 15;
  const int m0 = blockIdx.y * 128, n0 = blockIdx.x * 128;
  const int wm = (wave >> 1) * 64, wn = (wave & 1) * 64;

  f32x4 zero4 = {0.f, 0.f, 0.f, 0.f};
  f32x4 acc[4][4];
#pragma unroll
  for (int i = 0; i < 4; ++i)
#pragma unroll
    for (int j = 0; j < 4; ++j) acc[i][j] = zero4;

  int rowS[4], chkS[4];
#pragma unroll
  for (int ii = 0; ii < 4; ++ii) {
    int d = (wave * 4 + ii) * 64 + lane;
    rowS[ii] = d >> 3;
    chkS[ii] = (d & 7) ^ (rowS[ii] & 7);
  }

  for (int kt = 0; kt < K; kt += 64) {
    __syncthreads();
#pragma unroll
    for (int ii = 0; ii < 4; ++ii) {
      gld_lds16(A + (size_t)(m0 + rowS[ii]) * K + kt + chkS[ii] * 8,
                (char*)lA + (wave * 4 + ii) * 1024);
      gld_lds16(Bt + (size_t)(n0 + rowS[ii]) * K + kt + chkS[ii] * 8,
                (char*)lB + (wave * 4 + ii) * 1024);
    }
    __syncthreads();
#pragma unroll
    for (int kc = 0; kc < 2; ++kc) {
      short8 af[4], bf[4];
#pragma unroll
      for (int mt = 0; mt < 4; ++mt) {
        int r = wm + mt * 16 + l16;
        int c = (kc * 4 + quad) ^ (r & 7);
        af[mt] = *(const short8*)(lA + r * 64 + c * 8);
      }
#pragma unroll
      for (int nt = 0; nt < 4; ++nt) {
        int r = wn + nt * 16 + l16;
        int c = (kc * 4 + quad) ^ (r & 7);
        bf[nt] = *(const short8*)(lB + r * 64 + c * 8);
      }
#pragma unroll
      for (int mt = 0; mt < 4; ++mt)
#pragma unroll
        for (int nt = 0; nt < 4; ++nt)
          acc[mt][nt] = __builtin_amdgcn_mfma_f32_16x16x32_bf16(af[mt], bf[nt], acc[mt][nt], 0, 0, 0);
    }
  }

#pragma unroll
  for (int nt = 0; nt < 4; ++nt) {
    int gn = n0 + wn + nt * 16 + l16;
    float bv = bias[gn];
    if (gn < nSplit) {
#pragma unroll
      for (int mt = 0; mt < 4; ++mt) {
        int gmb = m0 + wm + mt * 16 + quad * 4;
#pragma unroll
        for (int reg = 0; reg < 4; ++reg) {
          size_t idx = (size_t)(gmb + reg) * nSplit + gn;
          float v = acc[mt][nt][reg] + bv;
          if (act == 1) v = 0.5f * v * (1.0f + erff(v * 0.70710678118654752f));
          if (gn < scaleN) v *= QSC;
          if (res) v += res[idx];
          if (outF) outF[idx] = v;
          if (outB) outB[idx] = f2b(v);
        }
      }
    } else {
#pragma unroll
      for (int mt = 0; mt < 4; ++mt) {
        int gmb = m0 + wm + mt * 16 + quad * 4;
        union { unsigned short u[4]; uint2 q; } pk;
#pragma unroll
        for (int reg = 0; reg < 4; ++reg) pk.u[reg] = f2b(acc[mt][nt][reg] + bv);
        *(uint2*)(outT + (size_t)(gn - nSplit) * M + gmb) = pk.q;
      }
    }
  }
}

// ---------------- 256x256 bf16 MFMA GEMM, Gray-code phases, minimal sync ----------------
// 8 waves (2M x 4N), BK=64, double-buffered 128KiB LDS (1 blk/CU; grid >= 256).
// Per K-tile: issue all 8 stage loads for tile t+1, then Gray-ordered quadrants
// (0,0)->(0,1)->(1,1)->(1,0) reloading only the operand that changed: 28
// ds_read_b128 for 64 MFMA (vs 48 in the symmetric order). No intra-tile
// barriers (phases of tile t only read buf[t&1], stage only writes buf^1 -> no
// cross-wave hazard); one vmcnt(0)+s_barrier per tile (stage loads issued ~full
// tile of compute earlier -> drain is cheap).
__global__ __launch_bounds__(512, 2) void gemm256(const ushort_t* __restrict__ A,
                                                  const ushort_t* __restrict__ Bt,
                                                  const float* __restrict__ bias,
                                                  const float* __restrict__ res,
                                                  float* __restrict__ outF,
                                                  ushort_t* __restrict__ outB,
                                                  ushort_t* __restrict__ outT,
                                                  int M, int N, int K, int act, int scaleN,
                                                  int nSplit) {
  __shared__ __align__(16) ushort_t sA[2][256 * 64];
  __shared__ __align__(16) ushort_t sB[2][256 * 64];
  const int tid = threadIdx.x;
  const int wave = tid >> 6, lane = tid & 63;
  const int quad = lane >> 4, l16 = lane & 15;
  const int m0 = blockIdx.y * 256, n0 = blockIdx.x * 256;
  const int wm = (wave >> 2) * 128, wn = (wave & 3) * 64;

  const ushort_t* Ab = A + (size_t)m0 * K;
  const ushort_t* Bb = Bt + (size_t)n0 * K;

  const int srow = tid >> 3;                        // 0..63
  const int schk = ((tid & 7) ^ (srow & 7)) << 3;   // swizzled element offset in row

#define STAGE_H(SRC, LD, KT, DST, H)                                          \
  do {                                                                        \
    gld_lds16((SRC) + (size_t)((H) * 128 + srow) * (LD) + (KT) + schk,        \
              (char*)(DST) + (H) * 16384 + tid * 16);                         \
    gld_lds16((SRC) + (size_t)((H) * 128 + 64 + srow) * (LD) + (KT) + schk,   \
              (char*)(DST) + (H) * 16384 + 8192 + tid * 16);                  \
  } while (0)

  f32x4 zero4 = {0.f, 0.f, 0.f, 0.f};
  f32x4 acc[8][4];
#pragma unroll
  for (int i = 0; i < 8; ++i)
#pragma unroll
    for (int j = 0; j < 4; ++j) acc[i][j] = zero4;

  const int NT = K >> 6;

  STAGE_H(Ab, K, 0, sA[0], 0);
  STAGE_H(Bb, K, 0, sB[0], 0);
  STAGE_H(Bb, K, 0, sB[0], 1);
  STAGE_H(Ab, K, 0, sA[0], 1);
  asm volatile("s_waitcnt vmcnt(0)" ::: "memory");
  __builtin_amdgcn_s_barrier();

#define LDA(MH)                                                                     \
  do {                                                                              \
    _Pragma("unroll") for (int mt = 0; mt < 4; ++mt)                                \
        _Pragma("unroll") for (int kc = 0; kc < 2; ++kc) {                          \
      int r = wm + ((MH) * 4 + mt) * 16 + l16;                                      \
      af[mt][kc] = *(const short8*)(curA + r * 64 + (((kc * 4 + quad) ^ (r & 7)) << 3)); \
    }                                                                               \
  } while (0)
#define LDB(NH)                                                                     \
  do {                                                                              \
    _Pragma("unroll") for (int nt = 0; nt < 2; ++nt)                                \
        _Pragma("unroll") for (int kc = 0; kc < 2; ++kc) {                          \
      int r = wn + ((NH) * 2 + nt) * 16 + l16;                                      \
      bf[nt][kc] = *(const short8*)(curB + r * 64 + (((kc * 4 + quad) ^ (r & 7)) << 3)); \
    }                                                                               \
  } while (0)
#define FMA(MH, NH)                                                                 \
  do {                                                                              \
    _Pragma("unroll") for (int kc = 0; kc < 2; ++kc)                                \
        _Pragma("unroll") for (int mt = 0; mt < 4; ++mt)                            \
            _Pragma("unroll") for (int nt = 0; nt < 2; ++nt)                        \
        acc[(MH) * 4 + mt][(NH) * 2 + nt] = __builtin_amdgcn_mfma_f32_16x16x32_bf16( \
            af[mt][kc], bf[nt][kc], acc[(MH) * 4 + mt][(NH) * 2 + nt], 0, 0, 0);    \
  } while (0)

  for (int t = 0; t < NT; ++t) {
    const ushort_t* curA = sA[t & 1];
    const ushort_t* curB = sB[t & 1];
    ushort_t* nxtA = sA[(t + 1) & 1];
    ushort_t* nxtB = sB[(t + 1) & 1];
    const int ktn = (t + 1) << 6;
    if (t + 1 < NT) {
      STAGE_H(Ab, K, ktn, nxtA, 0);
      STAGE_H(Bb, K, ktn, nxtB, 0);
      STAGE_H(Bb, K, ktn, nxtB, 1);
      STAGE_H(Ab, K, ktn, nxtA, 1);
    }
    short8 af[4][2], bf[2][2];
    LDA(0); LDB(0);
    FMA(0, 0);
    LDB(1);
    FMA(0, 1);
    LDA(1);
    FMA(1, 1);
    LDB(0);
    FMA(1, 0);
    asm volatile("s_waitcnt vmcnt(0)" ::: "memory");
    __builtin_amdgcn_s_barrier();
  }
#undef STAGE_H
#undef LDA
#undef LDB
#undef FMA

#pragma unroll
  for (int nt = 0; nt < 4; ++nt) {
    int gn = n0 + wn + nt * 16 + l16;
    float bv = bias[gn];
    if (gn < nSplit) {
#pragma unroll
      for (int mt = 0; mt < 8; ++mt) {
        int gmb = m0 + wm + mt * 16 + quad * 4;
#pragma unroll
        for (int reg = 0; reg < 4; ++reg) {
          size_t idx = (size_t)(gmb + reg) * nSplit + gn;
          float v = acc[mt][nt][reg] + bv;
          if (act == 1) v = 0.5f * v * (1.0f + erff(v * 0.70710678118654752f));
          if (gn < scaleN) v *= QSC;
          if (res) v += res[idx];
          if (outF) outF[idx] = v;
          if (outB) outB[idx] = f2b(v);
        }
      }
    } else {
#pragma unroll
      for (int mt = 0; mt < 8; ++mt) {
        int gmb = m0 + wm + mt * 16 + quad * 4;
        union { unsigned short u[4]; uint2 q2; } pk;
#pragma unroll
        for (int reg = 0; reg < 4; ++reg) pk.u[reg] = f2b(acc[mt][nt][reg] + bv);
        *(uint2*)(outT + (size_t)(gn - nSplit) * M + gmb) = pk.q2;
      }
    }
  }
}

// ---------------- 128x64 tile GEMM (single-buffer, round-0 proven) ----------------
__global__ __launch_bounds__(256) void gemm_n64(const ushort_t* __restrict__ A,
                                                const ushort_t* __restrict__ Bt,
                                                const float* __restrict__ bias,
                                                const float* __restrict__ res,
                                                float* __restrict__ outF,
                                                ushort_t* __restrict__ outB,
                                                int M, int N, int K, int act, int scaleN) {
  __shared__ __align__(16) ushort_t lA[128 * 64];
  __shared__ __align__(16) ushort_t lB[64 * 64];
  const int tid = threadIdx.x;
  const int wave = tid >> 6, lane = tid & 63;
  const int quad = lane >> 4, l16 = lane & 15;
  const int m0 = blockIdx.y * 128, n0 = blockIdx.x * 64;
  const int wm = wave * 32;

  f32x4 zero4 = {0.f, 0.f, 0.f, 0.f};
  f32x4 acc[2][4];
#pragma unroll
  for (int i = 0; i < 2; ++i)
#pragma unroll
    for (int j = 0; j < 4; ++j) acc[i][j] = zero4;

  int rowA[4], chkA[4], rowB[2], chkB[2];
#pragma unroll
  for (int ii = 0; ii < 4; ++ii) {
    int d = (wave * 4 + ii) * 64 + lane;
    rowA[ii] = d >> 3;
    chkA[ii] = (d & 7) ^ (rowA[ii] & 7);
  }
#pragma unroll
  for (int ii = 0; ii < 2; ++ii) {
    int d = (wave * 2 + ii) * 64 + lane;
    rowB[ii] = d >> 3;
    chkB[ii] = (d & 7) ^ (rowB[ii] & 7);
  }

  for (int kt = 0; kt < K; kt += 64) {
    __syncthreads();
#pragma unroll
    for (int ii = 0; ii < 4; ++ii)
      gld_lds16(A + (size_t)(m0 + rowA[ii]) * K + kt + chkA[ii] * 8,
                (char*)lA + (wave * 4 + ii) * 1024);
#pragma unroll
    for (int ii = 0; ii < 2; ++ii)
      gld_lds16(Bt + (size_t)(n0 + rowB[ii]) * K + kt + chkB[ii] * 8,
                (char*)lB + (wave * 2 + ii) * 1024);
    __syncthreads();
#pragma unroll
    for (int kc = 0; kc < 2; ++kc) {
      short8 af[2], bf[4];
#pragma unroll
      for (int mt = 0; mt < 2; ++mt) {
        int r = wm + mt * 16 + l16;
        int c = (kc * 4 + quad) ^ (r & 7);
        af[mt] = *(const short8*)(lA + r * 64 + c * 8);
      }
#pragma unroll
      for (int nt = 0; nt < 4; ++nt) {
        int r = nt * 16 + l16;
        int c = (kc * 4 + quad) ^ (r & 7);
        bf[nt] = *(const short8*)(lB + r * 64 + c * 8);
      }
#pragma unroll
      for (int mt = 0; mt < 2; ++mt)
#pragma unroll
        for (int nt = 0; nt < 4; ++nt)
          acc[mt][nt] = __builtin_amdgcn_mfma_f32_16x16x32_bf16(af[mt], bf[nt], acc[mt][nt], 0, 0, 0);
    }
  }

#pragma unroll
  for (int nt = 0; nt < 4; ++nt) {
    int gn = n0 + nt * 16 + l16;
    float bv = bias[gn];
#pragma unroll
    for (int mt = 0; mt < 2; ++mt) {
      int gmb = m0 + wm + mt * 16 + quad * 4;
#pragma unroll
      for (int reg = 0; reg < 4; ++reg) {
        size_t idx = (size_t)(gmb + reg) * N + gn;
        float v = acc[mt][nt][reg] + bv;
        if (act == 1) v = 0.5f * v * (1.0f + erff(v * 0.70710678118654752f));
        if (gn < scaleN) v *= QSC;
        if (res) v += res[idx];
        if (outF) outF[idx] = v;
        if (outB) outB[idx] = f2b(v);
      }
    }
  }
}

// ---------------- flash attention v5: MT=2 (128 q-rows/block) ----------------
// K/V double-buffered in LDS, staged once and consumed by TWO 64-row q
// sub-tiles with kf/vf fragments held in registers (shared) -> per 128 q-rows
// per kv-tile: 4 gld + 16 ds_read_b128 (vs 8 + 32 for two MT=1 blocks).
// No-max softmax as before; pad mask from global; stage-early drain-late.
template <int CAUSAL>
__global__ __launch_bounds__(256, 2) void attn5(const ushort_t* __restrict__ Qp, int ldQ,
                                                const ushort_t* __restrict__ Kp, int ldK,
                                                const ushort_t* __restrict__ Vt,
                                                const float* __restrict__ pmg,
                                                ushort_t* __restrict__ O) {
  __shared__ __align__(16) ushort_t lK[2][64 * 64];
  __shared__ __align__(16) ushort_t lV[2][64 * 64];
  __shared__ __align__(16) ushort_t lP[4][16 * 64];

  const int h = blockIdx.y, b = blockIdx.z;
  const int g = CAUSAL ? (15 - (int)blockIdx.x) : (int)blockIdx.x;  // heavy first
  const int tid = threadIdx.x;
  const int wave = tid >> 6, lane = tid & 63;
  const int quad = lane >> 4, l16 = lane & 15;
  const int g0 = g * 128;
  const float* pmb = pmg + b * S_LEN;

  short8 qf[2][2];
#pragma unroll
  for (int s = 0; s < 2; ++s) {
    const ushort_t* qb =
        Qp + ((size_t)(b * S_LEN) + g0 + s * 64 + wave * 16 + l16) * ldQ + h * 64;
    qf[s][0] = *(const short8*)(qb + quad * 8);
    qf[s][1] = *(const short8*)(qb + 32 + quad * 8);
  }

  f32x4 zero4 = {0.f, 0.f, 0.f, 0.f};
  f32x4 acc_o[2][4];
  float lsum[2][4];
#pragma unroll
  for (int s = 0; s < 2; ++s)
#pragma unroll
    for (int nt = 0; nt < 4; ++nt) {
      acc_o[s][nt] = zero4;
      lsum[s][nt] = 0.f;
    }

  const int nkv = CAUSAL ? (2 * g + 2) : (S_LEN / 64);

  int srow[2], scs[2];
#pragma unroll
  for (int ii = 0; ii < 2; ++ii) {
    int slot = (wave * 2 + ii) * 64 + lane;
    srow[ii] = slot >> 3;
    scs[ii] = ((slot & 7) ^ (srow[ii] & 7)) * 8;
  }

#define STAGE_KV(KV0, BUF)                                                            \
  do {                                                                                \
    _Pragma("unroll") for (int ii = 0; ii < 2; ++ii) {                                \
      gld_lds16(Kp + (size_t)(b * S_LEN + (KV0) + srow[ii]) * ldK + h * 64 + scs[ii], \
                (char*)lK[BUF] + (wave * 2 + ii) * 1024);                             \
      gld_lds16(Vt + (size_t)(h * 64 + srow[ii]) * 4096 + b * S_LEN + (KV0) + scs[ii],\
                (char*)lV[BUF] + (wave * 2 + ii) * 1024);                             \
    }                                                                                 \
  } while (0)

  STAGE_KV(0, 0);
  __syncthreads();

  int cur = 0;
  for (int kv = 0; kv < nkv; ++kv) {
    const int kv0 = kv * 64;
    if (kv + 1 < nkv) STAGE_KV(kv0 + 64, cur ^ 1);

    float pmv[4];
#pragma unroll
    for (int nt = 0; nt < 4; ++nt) pmv[nt] = pmb[kv0 + nt * 16 + l16];

    const ushort_t* cK = lK[cur];
    const ushort_t* cV = lV[cur];

    // fragments shared by both q sub-tiles
    short8 kf[2][4], vf[2][4];
#pragma unroll
    for (int kc = 0; kc < 2; ++kc)
#pragma unroll
      for (int nt = 0; nt < 4; ++nt) {
        int r = nt * 16 + l16;
        int c = (kc * 4 + quad) ^ (r & 7);
        kf[kc][nt] = *(const short8*)(cK + r * 64 + c * 8);
        vf[kc][nt] = *(const short8*)(cV + r * 64 + c * 8);
      }

#pragma unroll
    for (int s = 0; s < 2; ++s) {
      if (CAUSAL && kv > 2 * g + s) continue;  // fully masked sub-tile

      f32x4 sacc[4];
#pragma unroll
      for (int nt = 0; nt < 4; ++nt) sacc[nt] = zero4;
#pragma unroll
      for (int kc = 0; kc < 2; ++kc)
#pragma unroll
        for (int nt = 0; nt < 4; ++nt)
          sacc[nt] = __builtin_amdgcn_mfma_f32_16x16x32_bf16(qf[s][kc], kf[kc][nt], sacc[nt], 0, 0, 0);

      const int qbase = g0 + s * 64 + wave * 16 + quad * 4;
      const bool diag = CAUSAL && (kv == 2 * g + s);
#pragma unroll
      for (int nt = 0; nt < 4; ++nt) {
        int kk = kv0 + nt * 16 + l16;
#pragma unroll
        for (int reg = 0; reg < 4; ++reg) {
          float sv = sacc[nt][reg] + pmv[nt];
          if (diag && kk > qbase + reg) sv = NEGF;
          float p = EXP2(sv);
          lsum[s][reg] += p;
          int q = quad * 4 + reg;
          int cc = (nt * 2 + (l16 >> 3)) ^ (q & 7);
          lP[wave][q * 64 + cc * 8 + (l16 & 7)] = f2b(p);
        }
      }

#pragma unroll
      for (int kc = 0; kc < 2; ++kc) {
        int cp = (kc * 4 + quad) ^ (l16 & 7);
        short8 pf = *(const short8*)(&lP[wave][l16 * 64 + cp * 8]);
#pragma unroll
        for (int nt = 0; nt < 4; ++nt)
          acc_o[s][nt] = __builtin_amdgcn_mfma_f32_16x16x32_bf16(pf, vf[kc][nt], acc_o[s][nt], 0, 0, 0);
      }
    }
    __syncthreads();
    cur ^= 1;
  }  // kv
#undef STAGE_KV

#pragma unroll
  for (int s = 0; s < 2; ++s) {
    float inv[4];
#pragma unroll
    for (int reg = 0; reg < 4; ++reg) {
      float t = lsum[s][reg];
      t += __shfl_xor(t, 1);
      t += __shfl_xor(t, 2);
      t += __shfl_xor(t, 4);
      t += __shfl_xor(t, 8);
      inv[reg] = 1.0f / t;
    }
#pragma unroll
    for (int nt = 0; nt < 4; ++nt)
#pragma unroll
      for (int reg = 0; reg < 4; ++reg) {
        int qr = g0 + s * 64 + wave * 16 + quad * 4 + reg;
        O[((size_t)(b * S_LEN) + qr) * 1024 + h * 64 + nt * 16 + l16] =
            f2b(acc_o[s][nt][reg] * inv[reg]);
      }
  }
}

// ---------------- launch ----------------
extern "C" void kernel_launch(void* const* d_in, const int* in_sizes, int n_in,
                              void* d_out, int out_size, void* d_ws, size_t ws_size,
                              hipStream_t stream) {
  (void)in_sizes; (void)n_in; (void)out_size; (void)ws_size;
  const size_t MB = 1024 * 1024;
  char* w = (char*)d_ws;
  ushort_t* qkv1T = (ushort_t*)(w + 0);        // [3072][1024] bf16, 6MB
  ushort_t* o1T = (ushort_t*)(w + 6 * MB);     // 2MB
  ushort_t* q2T = (ushort_t*)(w + 8 * MB);     // 2MB
  ushort_t* k2v2T = (ushort_t*)(w + 10 * MB);  // [2048][1024], 4MB
  ushort_t* o2T = (ushort_t*)(w + 14 * MB);    // 2MB
  ushort_t* m1T = (ushort_t*)(w + 16 * MB);    // [4096][1024], 8MB
  ushort_t* m2T = (ushort_t*)(w + 24 * MB);    // [1024][4096], 8MB
  float* bias3 = (float*)(w + 32 * MB);        // 12KB
  float* bias2 = (float*)(w + 32 * MB + 64 * 1024);
  float* pmA = (float*)(w + 32 * MB + 128 * 1024);  // 16KB self pad mask
  float* pmB = (float*)(w + 32 * MB + 160 * 1024);  // 16KB cross pad mask
  ushort_t* xb = (ushort_t*)(w + 33 * MB);     // 8MB; reused later as hlnb
  ushort_t* QKb = (ushort_t*)(w + 41 * MB);    // [4096][2048], 16MB; later Q2b+K2b
  ushort_t* Vt = (ushort_t*)(w + 57 * MB);     // [1024][4096], 8MB (self then cross)
  ushort_t* Ob = (ushort_t*)(w + 65 * MB);     // 8MB
  ushort_t* encb = (ushort_t*)(w + 73 * MB);   // 8MB
  float* xf = (float*)(w + 81 * MB);           // 16MB (post-LN1 x; later r)
  float* hf = (float*)(w + 97 * MB);           // 16MB (x+attn; LN2 in place)
  ushort_t* m1b = (ushort_t*)(w + 113 * MB);   // 32MB
  ushort_t* hlnb = xb;
  ushort_t* Q2b = QKb;                  // [4096][1024]
  ushort_t* K2b = QKb + 4 * MB;         // +8MB bytes -> [4096][1024]

  dim3 B256(256);
  dim3 B512(512);
  // weight conversions
  P8 p8;
  p8.s[0] = (const float*)d_in[7];  p8.d[0] = qkv1T;
  p8.s[1] = (const float*)d_in[9];  p8.d[1] = qkv1T + 1024 * 1024;
  p8.s[2] = (const float*)d_in[11]; p8.d[2] = qkv1T + 2 * 1024 * 1024;
  p8.s[3] = (const float*)d_in[13]; p8.d[3] = o1T;
  p8.s[4] = (const float*)d_in[17]; p8.d[4] = q2T;
  p8.s[5] = (const float*)d_in[19]; p8.d[5] = k2v2T;
  p8.s[6] = (const float*)d_in[21]; p8.d[6] = k2v2T + 1024 * 1024;
  p8.s[7] = (const float*)d_in[23]; p8.d[7] = o2T;
  wtrans8<<<dim3(32, 32, 8), B256, 0, stream>>>(p8);
  wtrans<<<dim3(128, 32), B256, 0, stream>>>((const float*)d_in[27], m1T, 1024, 4096);
  wtrans<<<dim3(32, 128), B256, 0, stream>>>((const float*)d_in[29], m2T, 4096, 1024);
  f2bcvt<<<4096, B256, 0, stream>>>((const float*)d_in[0], encb);
  bcat<<<12, B256, 0, stream>>>(bias3, (const float*)d_in[8], (const float*)d_in[10],
                                (const float*)d_in[12], 1024, 1024);
  bcat<<<8, B256, 0, stream>>>(bias2, (const float*)d_in[20], (const float*)d_in[22],
                               (const float*)d_in[22], 1024, 1024);
  padmask<<<16, B256, 0, stream>>>((const int*)d_in[2], (const int*)d_in[1], pmA, pmB);

  // embed + LN1
  embed_ln<<<4096, B256, 0, stream>>>((const int*)d_in[2], (const float*)d_in[3],
                                      (const float*)d_in[4], (const float*)d_in[5],
                                      (const float*)d_in[6], xf, xb);
  // fused QKV1 (Q cols scaled, V cols transposed)
  gemm_bt<<<dim3(24, 32), B256, 0, stream>>>(xb, qkv1T, bias3, nullptr, nullptr, QKb, Vt,
                                             4096, 3072, 1024, 0, 1024, 2048);
  attn5<1><<<dim3(16, 16, 2), B256, 0, stream>>>(QKb, 2048, QKb + 1024, 2048, Vt, pmA, Ob);
  gemm_n64<<<dim3(16, 32), B256, 0, stream>>>(Ob, o1T, (const float*)d_in[14], xf, hf, nullptr,
                                              4096, 1024, 1024, 0, 0);
  ln_fwd<<<4096, B256, 0, stream>>>(hf, (const float*)d_in[15], (const float*)d_in[16], hf, hlnb);
  // cross-attn projections
  gemm_n64<<<dim3(16, 32), B256, 0, stream>>>(hlnb, q2T, (const float*)d_in[18], nullptr, nullptr,
                                              Q2b, 4096, 1024, 1024, 0, 1024);
  gemm_bt<<<dim3(16, 32), B256, 0, stream>>>(encb, k2v2T, bias2, nullptr, nullptr, K2b, Vt,
                                             4096, 2048, 1024, 0, 0, 1024);
  attn5<0><<<dim3(16, 16, 2), B256, 0, stream>>>(Q2b, 1024, K2b, 1024, Vt, pmB, Ob);
  gemm_n64<<<dim3(16, 32), B256, 0, stream>>>(Ob, o2T, (const float*)d_in[24], hf, xf, nullptr,
                                              4096, 1024, 1024, 0, 0);
  ln_fwd<<<4096, B256, 0, stream>>>(xf, (const float*)d_in[25], (const float*)d_in[26], nullptr,
                                    hlnb);
  // MLP
  gemm256<<<dim3(16, 16), B512, 0, stream>>>(hlnb, m1T, (const float*)d_in[28], nullptr, nullptr,
                                             m1b, nullptr, 4096, 4096, 1024, 1, 0, 4096);
  gemm_n64<<<dim3(16, 32), B256, 0, stream>>>(m1b, m2T, (const float*)d_in[30], xf, (float*)d_out,
                                              nullptr, 4096, 1024, 4096, 0, 0);
}

// Round 5
// 688.646 us; speedup vs baseline: 1.0335x; 1.0289x over previous
//
#include <hip/hip_runtime.h>
#include <hip/hip_bf16.h>

#define S_LEN 2048
#define NEGF -1000000000.0f
#define QSC 0.18033688f  // 0.125 * log2(e)

typedef unsigned short ushort_t;
typedef __attribute__((ext_vector_type(8))) short short8;
typedef __attribute__((ext_vector_type(4))) float f32x4;

#if defined(__has_builtin)
#if __has_builtin(__builtin_amdgcn_exp2f)
#define EXP2 __builtin_amdgcn_exp2f
#endif
#endif
#ifndef EXP2
#define EXP2 exp2f
#endif

__device__ __forceinline__ unsigned short f2b(float f) {
  unsigned int u = __float_as_uint(f);
  return (unsigned short)((u + 0x7fffu + ((u >> 16) & 1u)) >> 16);
}

__device__ __forceinline__ void gld_lds16(const void* g, void* l) {
  __builtin_amdgcn_global_load_lds((__attribute__((address_space(1))) unsigned int*)g,
                                   (__attribute__((address_space(3))) unsigned int*)l, 16, 0, 0);
}

// ---------------- weight transpose f32[K,N] -> bf16[N,K] ----------------
__device__ __forceinline__ void wtrans_body(const float* __restrict__ W,
                                            ushort_t* __restrict__ Wt, int K, int N,
                                            int bx, int by) {
  __shared__ float t[32][33];
  int n0 = bx * 32, k0 = by * 32;
  int tx = threadIdx.x & 31, ty = threadIdx.x >> 5;
#pragma unroll
  for (int i = 0; i < 32; i += 8)
    t[ty + i][tx] = W[(size_t)(k0 + ty + i) * N + n0 + tx];
  __syncthreads();
#pragma unroll
  for (int i = 0; i < 32; i += 8)
    Wt[(size_t)(n0 + ty + i) * K + k0 + tx] = f2b(t[tx][ty + i]);
}

__global__ __launch_bounds__(256) void wtrans(const float* __restrict__ W,
                                              ushort_t* __restrict__ Wt, int K, int N) {
  wtrans_body(W, Wt, K, N, blockIdx.x, blockIdx.y);
}

struct P8 {
  const float* s[8];
  ushort_t* d[8];
};
__global__ __launch_bounds__(256) void wtrans8(P8 p) {
  wtrans_body(p.s[blockIdx.z], p.d[blockIdx.z], 1024, 1024, blockIdx.x, blockIdx.y);
}

__global__ __launch_bounds__(256) void f2bcvt(const float* __restrict__ in,
                                              ushort_t* __restrict__ out) {
  size_t i = ((size_t)blockIdx.x * 256 + threadIdx.x) * 4;
  float4 v = *(const float4*)(in + i);
  union { unsigned short u[4]; uint2 q; } pk;
  pk.u[0] = f2b(v.x); pk.u[1] = f2b(v.y); pk.u[2] = f2b(v.z); pk.u[3] = f2b(v.w);
  *(uint2*)(out + i) = pk.q;
}

__global__ __launch_bounds__(256) void bcat(float* __restrict__ dst, const float* __restrict__ a,
                                            const float* __restrict__ b,
                                            const float* __restrict__ c, int n0, int n1) {
  int i = blockIdx.x * 256 + threadIdx.x;
  float v = (i < n0) ? a[i] : (i < n0 + n1 ? b[i - n0] : c[i - n0 - n1]);
  dst[i] = v;
}

// pad masks -> global f32
__global__ __launch_bounds__(256) void padmask(const int* __restrict__ tids,
                                               const int* __restrict__ iids,
                                               float* __restrict__ pmA,
                                               float* __restrict__ pmB) {
  int i = blockIdx.x * 256 + threadIdx.x;
  pmA[i] = (tids[i] == 0) ? NEGF : 0.0f;
  pmB[i] = (iids[i] == 0) ? NEGF : 0.0f;
}

// ---------------- layernorm ----------------
__device__ __forceinline__ void row_stats(float s, float ss, float* outMean, float* outRstd) {
  __shared__ float red[8];
#pragma unroll
  for (int o = 32; o > 0; o >>= 1) {
    s += __shfl_down(s, o);
    ss += __shfl_down(ss, o);
  }
  int wave = threadIdx.x >> 6, lane = threadIdx.x & 63;
  if (lane == 0) { red[wave] = s; red[4 + wave] = ss; }
  __syncthreads();
  if (threadIdx.x == 0) {
    float S0 = red[0] + red[1] + red[2] + red[3];
    float S1 = red[4] + red[5] + red[6] + red[7];
    float mean = S0 * (1.0f / 1024.0f);
    float var = S1 * (1.0f / 1024.0f) - mean * mean;
    red[0] = mean;
    red[1] = rsqrtf(var + 1e-5f);
  }
  __syncthreads();
  *outMean = red[0];
  *outRstd = red[1];
}

__global__ __launch_bounds__(256) void embed_ln(const int* __restrict__ tids,
                                                const float* __restrict__ tok,
                                                const float* __restrict__ pos,
                                                const float* __restrict__ g,
                                                const float* __restrict__ be,
                                                float* __restrict__ xf,
                                                ushort_t* __restrict__ xb) {
  int row = blockIdx.x;
  int s = row & (S_LEN - 1);
  int id = tids[row];
  int c = threadIdx.x * 4;
  float4 v = *(const float4*)(tok + (size_t)id * 1024 + c);
  float4 p = *(const float4*)(pos + (size_t)s * 1024 + c);
  v.x += p.x; v.y += p.y; v.z += p.z; v.w += p.w;
  float mean, rstd;
  row_stats(v.x + v.y + v.z + v.w, v.x * v.x + v.y * v.y + v.z * v.z + v.w * v.w, &mean, &rstd);
  float4 gv = *(const float4*)(g + c);
  float4 bv = *(const float4*)(be + c);
  float4 o;
  o.x = (v.x - mean) * rstd * gv.x + bv.x;
  o.y = (v.y - mean) * rstd * gv.y + bv.y;
  o.z = (v.z - mean) * rstd * gv.z + bv.z;
  o.w = (v.w - mean) * rstd * gv.w + bv.w;
  *(float4*)(xf + (size_t)row * 1024 + c) = o;
  union { unsigned short u[4]; uint2 q; } pk;
  pk.u[0] = f2b(o.x); pk.u[1] = f2b(o.y); pk.u[2] = f2b(o.z); pk.u[3] = f2b(o.w);
  *(uint2*)(xb + (size_t)row * 1024 + c) = pk.q;
}

__global__ __launch_bounds__(256) void ln_fwd(const float* in, const float* __restrict__ g,
                                              const float* __restrict__ be, float* outF,
                                              ushort_t* __restrict__ outB) {
  int row = blockIdx.x;
  int c = threadIdx.x * 4;
  float4 v = *(const float4*)(in + (size_t)row * 1024 + c);
  float mean, rstd;
  row_stats(v.x + v.y + v.z + v.w, v.x * v.x + v.y * v.y + v.z * v.z + v.w * v.w, &mean, &rstd);
  float4 gv = *(const float4*)(g + c);
  float4 bv = *(const float4*)(be + c);
  float4 o;
  o.x = (v.x - mean) * rstd * gv.x + bv.x;
  o.y = (v.y - mean) * rstd * gv.y + bv.y;
  o.z = (v.z - mean) * rstd * gv.z + bv.z;
  o.w = (v.w - mean) * rstd * gv.w + bv.w;
  if (outF) *(float4*)(outF + (size_t)row * 1024 + c) = o;
  union { unsigned short u[4]; uint2 q; } pk;
  pk.u[0] = f2b(o.x); pk.u[1] = f2b(o.y); pk.u[2] = f2b(o.z); pk.u[3] = f2b(o.w);
  *(uint2*)(outB + (size_t)row * 1024 + c) = pk.q;
}

// ---------------- 128x128 bf16 MFMA GEMM (2-phase, proven) ----------------
__global__ __launch_bounds__(256) void gemm_bt(const ushort_t* __restrict__ A,
                                               const ushort_t* __restrict__ Bt,
                                               const float* __restrict__ bias,
                                               const float* __restrict__ res,
                                               float* __restrict__ outF,
                                               ushort_t* __restrict__ outB,
                                               ushort_t* __restrict__ outT,
                                               int M, int N, int K, int act, int scaleN,
                                               int nSplit) {
  __shared__ __align__(16) ushort_t lA[128 * 64];
  __shared__ __align__(16) ushort_t lB[128 * 64];
  const int tid = threadIdx.x;
  const int wave = tid >> 6, lane = tid & 63;
  const int quad = lane >> 4, l16 = lane & 15;
  const int m0 = blockIdx.y * 128, n0 = blockIdx.x * 128;
  const int wm = (wave >> 1) * 64, wn = (wave & 1) * 64;

  f32x4 zero4 = {0.f, 0.f, 0.f, 0.f};
  f32x4 acc[4][4];
#pragma unroll
  for (int i = 0; i < 4; ++i)
#pragma unroll
    for (int j = 0; j < 4; ++j) acc[i][j] = zero4;

  int rowS[4], chkS[4];
#pragma unroll
  for (int ii = 0; ii < 4; ++ii) {
    int d = (wave * 4 + ii) * 64 + lane;
    rowS[ii] = d >> 3;
    chkS[ii] = (d & 7) ^ (rowS[ii] & 7);
  }

  for (int kt = 0; kt < K; kt += 64) {
    __syncthreads();
#pragma unroll
    for (int ii = 0; ii < 4; ++ii) {
      gld_lds16(A + (size_t)(m0 + rowS[ii]) * K + kt + chkS[ii] * 8,
                (char*)lA + (wave * 4 + ii) * 1024);
      gld_lds16(Bt + (size_t)(n0 + rowS[ii]) * K + kt + chkS[ii] * 8,
                (char*)lB + (wave * 4 + ii) * 1024);
    }
    __syncthreads();
#pragma unroll
    for (int kc = 0; kc < 2; ++kc) {
      short8 af[4], bf[4];
#pragma unroll
      for (int mt = 0; mt < 4; ++mt) {
        int r = wm + mt * 16 + l16;
        int c = (kc * 4 + quad) ^ (r & 7);
        af[mt] = *(const short8*)(lA + r * 64 + c * 8);
      }
#pragma unroll
      for (int nt = 0; nt < 4; ++nt) {
        int r = wn + nt * 16 + l16;
        int c = (kc * 4 + quad) ^ (r & 7);
        bf[nt] = *(const short8*)(lB + r * 64 + c * 8);
      }
#pragma unroll
      for (int mt = 0; mt < 4; ++mt)
#pragma unroll
        for (int nt = 0; nt < 4; ++nt)
          acc[mt][nt] = __builtin_amdgcn_mfma_f32_16x16x32_bf16(af[mt], bf[nt], acc[mt][nt], 0, 0, 0);
    }
  }

#pragma unroll
  for (int nt = 0; nt < 4; ++nt) {
    int gn = n0 + wn + nt * 16 + l16;
    float bv = bias[gn];
    if (gn < nSplit) {
#pragma unroll
      for (int mt = 0; mt < 4; ++mt) {
        int gmb = m0 + wm + mt * 16 + quad * 4;
#pragma unroll
        for (int reg = 0; reg < 4; ++reg) {
          size_t idx = (size_t)(gmb + reg) * nSplit + gn;
          float v = acc[mt][nt][reg] + bv;
          if (act == 1) v = 0.5f * v * (1.0f + erff(v * 0.70710678118654752f));
          if (gn < scaleN) v *= QSC;
          if (res) v += res[idx];
          if (outF) outF[idx] = v;
          if (outB) outB[idx] = f2b(v);
        }
      }
    } else {
#pragma unroll
      for (int mt = 0; mt < 4; ++mt) {
        int gmb = m0 + wm + mt * 16 + quad * 4;
        union { unsigned short u[4]; uint2 q; } pk;
#pragma unroll
        for (int reg = 0; reg < 4; ++reg) pk.u[reg] = f2b(acc[mt][nt][reg] + bv);
        *(uint2*)(outT + (size_t)(gn - nSplit) * M + gmb) = pk.q;
      }
    }
  }
}

// ---------------- 128x64 tile GEMM (single-buffer, round-0 proven) ----------------
__global__ __launch_bounds__(256) void gemm_n64(const ushort_t* __restrict__ A,
                                                const ushort_t* __restrict__ Bt,
                                                const float* __restrict__ bias,
                                                const float* __restrict__ res,
                                                float* __restrict__ outF,
                                                ushort_t* __restrict__ outB,
                                                int M, int N, int K, int act, int scaleN) {
  __shared__ __align__(16) ushort_t lA[128 * 64];
  __shared__ __align__(16) ushort_t lB[64 * 64];
  const int tid = threadIdx.x;
  const int wave = tid >> 6, lane = tid & 63;
  const int quad = lane >> 4, l16 = lane & 15;
  const int m0 = blockIdx.y * 128, n0 = blockIdx.x * 64;
  const int wm = wave * 32;

  f32x4 zero4 = {0.f, 0.f, 0.f, 0.f};
  f32x4 acc[2][4];
#pragma unroll
  for (int i = 0; i < 2; ++i)
#pragma unroll
    for (int j = 0; j < 4; ++j) acc[i][j] = zero4;

  int rowA[4], chkA[4], rowB[2], chkB[2];
#pragma unroll
  for (int ii = 0; ii < 4; ++ii) {
    int d = (wave * 4 + ii) * 64 + lane;
    rowA[ii] = d >> 3;
    chkA[ii] = (d & 7) ^ (rowA[ii] & 7);
  }
#pragma unroll
  for (int ii = 0; ii < 2; ++ii) {
    int d = (wave * 2 + ii) * 64 + lane;
    rowB[ii] = d >> 3;
    chkB[ii] = (d & 7) ^ (rowB[ii] & 7);
  }

  for (int kt = 0; kt < K; kt += 64) {
    __syncthreads();
#pragma unroll
    for (int ii = 0; ii < 4; ++ii)
      gld_lds16(A + (size_t)(m0 + rowA[ii]) * K + kt + chkA[ii] * 8,
                (char*)lA + (wave * 4 + ii) * 1024);
#pragma unroll
    for (int ii = 0; ii < 2; ++ii)
      gld_lds16(Bt + (size_t)(n0 + rowB[ii]) * K + kt + chkB[ii] * 8,
                (char*)lB + (wave * 2 + ii) * 1024);
    __syncthreads();
#pragma unroll
    for (int kc = 0; kc < 2; ++kc) {
      short8 af[2], bf[4];
#pragma unroll
      for (int mt = 0; mt < 2; ++mt) {
        int r = wm + mt * 16 + l16;
        int c = (kc * 4 + quad) ^ (r & 7);
        af[mt] = *(const short8*)(lA + r * 64 + c * 8);
      }
#pragma unroll
      for (int nt = 0; nt < 4; ++nt) {
        int r = nt * 16 + l16;
        int c = (kc * 4 + quad) ^ (r & 7);
        bf[nt] = *(const short8*)(lB + r * 64 + c * 8);
      }
#pragma unroll
      for (int mt = 0; mt < 2; ++mt)
#pragma unroll
        for (int nt = 0; nt < 4; ++nt)
          acc[mt][nt] = __builtin_amdgcn_mfma_f32_16x16x32_bf16(af[mt], bf[nt], acc[mt][nt], 0, 0, 0);
    }
  }

#pragma unroll
  for (int nt = 0; nt < 4; ++nt) {
    int gn = n0 + nt * 16 + l16;
    float bv = bias[gn];
#pragma unroll
    for (int mt = 0; mt < 2; ++mt) {
      int gmb = m0 + wm + mt * 16 + quad * 4;
#pragma unroll
      for (int reg = 0; reg < 4; ++reg) {
        size_t idx = (size_t)(gmb + reg) * N + gn;
        float v = acc[mt][nt][reg] + bv;
        if (act == 1) v = 0.5f * v * (1.0f + erff(v * 0.70710678118654752f));
        if (gn < scaleN) v *= QSC;
        if (res) v += res[idx];
        if (outF) outF[idx] = v;
        if (outB) outB[idx] = f2b(v);
      }
    }
  }
}

// ---------------- flash attention v6: work-balanced q-tile pairing ----------------
// MT=2 (two 64-row q sub-tiles share each staged K/V tile, kf/vf in registers).
// CAUSAL: block bx pairs q-tiles (31-bx) [heavy] and (bx) [light]; kv stream
// runs 0..31-bx; light sub-tile participates only while kv <= bx. Every block
// computes exactly 33 tile-units (vs 3..63 with adjacent pairing) -> causal
// duration drops from the 32-tile critical path to the balanced-throughput
// bound (~half). CROSS: adjacent pairing (2bx, 2bx+1), full range - identical
// numerics to attn5. No-max softmax (Q pre-scaled by 0.125*log2e); pad mask
// from global; K/V double-buffered, stage-early drain-late.
template <int CAUSAL>
__global__ __launch_bounds__(256, 2) void attn6(const ushort_t* __restrict__ Qp, int ldQ,
                                                const ushort_t* __restrict__ Kp, int ldK,
                                                const ushort_t* __restrict__ Vt,
                                                const float* __restrict__ pmg,
                                                ushort_t* __restrict__ O) {
  __shared__ __align__(16) ushort_t lK[2][64 * 64];
  __shared__ __align__(16) ushort_t lV[2][64 * 64];
  __shared__ __align__(16) ushort_t lP[4][16 * 64];

  const int h = blockIdx.y, b = blockIdx.z;
  const int bx = blockIdx.x;
  const int gq[2] = {CAUSAL ? (31 - bx) : (2 * bx), CAUSAL ? bx : (2 * bx + 1)};
  const int tid = threadIdx.x;
  const int wave = tid >> 6, lane = tid & 63;
  const int quad = lane >> 4, l16 = lane & 15;
  const float* pmb = pmg + b * S_LEN;

  short8 qf[2][2];
#pragma unroll
  for (int s = 0; s < 2; ++s) {
    const ushort_t* qb =
        Qp + ((size_t)(b * S_LEN) + gq[s] * 64 + wave * 16 + l16) * ldQ + h * 64;
    qf[s][0] = *(const short8*)(qb + quad * 8);
    qf[s][1] = *(const short8*)(qb + 32 + quad * 8);
  }

  f32x4 zero4 = {0.f, 0.f, 0.f, 0.f};
  f32x4 acc_o[2][4];
  float lsum[2][4];
#pragma unroll
  for (int s = 0; s < 2; ++s)
#pragma unroll
    for (int nt = 0; nt < 4; ++nt) {
      acc_o[s][nt] = zero4;
      lsum[s][nt] = 0.f;
    }

  const int nkv = CAUSAL ? (gq[0] + 1) : (S_LEN / 64);

  int srow[2], scs[2];
#pragma unroll
  for (int ii = 0; ii < 2; ++ii) {
    int slot = (wave * 2 + ii) * 64 + lane;
    srow[ii] = slot >> 3;
    scs[ii] = ((slot & 7) ^ (srow[ii] & 7)) * 8;
  }

#define STAGE_KV(KV0, BUF)                                                            \
  do {                                                                                \
    _Pragma("unroll") for (int ii = 0; ii < 2; ++ii) {                                \
      gld_lds16(Kp + (size_t)(b * S_LEN + (KV0) + srow[ii]) * ldK + h * 64 + scs[ii], \
                (char*)lK[BUF] + (wave * 2 + ii) * 1024);                             \
      gld_lds16(Vt + (size_t)(h * 64 + srow[ii]) * 4096 + b * S_LEN + (KV0) + scs[ii],\
                (char*)lV[BUF] + (wave * 2 + ii) * 1024);                             \
    }                                                                                 \
  } while (0)

  STAGE_KV(0, 0);
  __syncthreads();

  int cur = 0;
  for (int kv = 0; kv < nkv; ++kv) {
    const int kv0 = kv * 64;
    if (kv + 1 < nkv) STAGE_KV(kv0 + 64, cur ^ 1);

    float pmv[4];
#pragma unroll
    for (int nt = 0; nt < 4; ++nt) pmv[nt] = pmb[kv0 + nt * 16 + l16];

    const ushort_t* cK = lK[cur];
    const ushort_t* cV = lV[cur];

    // fragments shared by both q sub-tiles
    short8 kf[2][4], vf[2][4];
#pragma unroll
    for (int kc = 0; kc < 2; ++kc)
#pragma unroll
      for (int nt = 0; nt < 4; ++nt) {
        int r = nt * 16 + l16;
        int c = (kc * 4 + quad) ^ (r & 7);
        kf[kc][nt] = *(const short8*)(cK + r * 64 + c * 8);
        vf[kc][nt] = *(const short8*)(cV + r * 64 + c * 8);
      }

#pragma unroll
    for (int s = 0; s < 2; ++s) {
      if (CAUSAL && kv > gq[s]) continue;  // fully masked sub-tile (uniform branch)

      f32x4 sacc[4];
#pragma unroll
      for (int nt = 0; nt < 4; ++nt) sacc[nt] = zero4;
#pragma unroll
      for (int kc = 0; kc < 2; ++kc)
#pragma unroll
        for (int nt = 0; nt < 4; ++nt)
          sacc[nt] = __builtin_amdgcn_mfma_f32_16x16x32_bf16(qf[s][kc], kf[kc][nt], sacc[nt], 0, 0, 0);

      const int qbase = gq[s] * 64 + wave * 16 + quad * 4;
      const bool diag = CAUSAL && (kv == gq[s]);
#pragma unroll
      for (int nt = 0; nt < 4; ++nt) {
        int kk = kv0 + nt * 16 + l16;
#pragma unroll
        for (int reg = 0; reg < 4; ++reg) {
          float sv = sacc[nt][reg] + pmv[nt];
          if (diag && kk > qbase + reg) sv = NEGF;
          float p = EXP2(sv);
          lsum[s][reg] += p;
          int q = quad * 4 + reg;
          int cc = (nt * 2 + (l16 >> 3)) ^ (q & 7);
          lP[wave][q * 64 + cc * 8 + (l16 & 7)] = f2b(p);
        }
      }

#pragma unroll
      for (int kc = 0; kc < 2; ++kc) {
        int cp = (kc * 4 + quad) ^ (l16 & 7);
        short8 pf = *(const short8*)(&lP[wave][l16 * 64 + cp * 8]);
#pragma unroll
        for (int nt = 0; nt < 4; ++nt)
          acc_o[s][nt] = __builtin_amdgcn_mfma_f32_16x16x32_bf16(pf, vf[kc][nt], acc_o[s][nt], 0, 0, 0);
      }
    }
    __syncthreads();
    cur ^= 1;
  }  // kv
#undef STAGE_KV

#pragma unroll
  for (int s = 0; s < 2; ++s) {
    float inv[4];
#pragma unroll
    for (int reg = 0; reg < 4; ++reg) {
      float t = lsum[s][reg];
      t += __shfl_xor(t, 1);
      t += __shfl_xor(t, 2);
      t += __shfl_xor(t, 4);
      t += __shfl_xor(t, 8);
      inv[reg] = 1.0f / t;
    }
#pragma unroll
    for (int nt = 0; nt < 4; ++nt)
#pragma unroll
      for (int reg = 0; reg < 4; ++reg) {
        int qr = gq[s] * 64 + wave * 16 + quad * 4 + reg;
        O[((size_t)(b * S_LEN) + qr) * 1024 + h * 64 + nt * 16 + l16] =
            f2b(acc_o[s][nt][reg] * inv[reg]);
      }
  }
}

// ---------------- launch ----------------
extern "C" void kernel_launch(void* const* d_in, const int* in_sizes, int n_in,
                              void* d_out, int out_size, void* d_ws, size_t ws_size,
                              hipStream_t stream) {
  (void)in_sizes; (void)n_in; (void)out_size; (void)ws_size;
  const size_t MB = 1024 * 1024;
  char* w = (char*)d_ws;
  ushort_t* qkv1T = (ushort_t*)(w + 0);        // [3072][1024] bf16, 6MB
  ushort_t* o1T = (ushort_t*)(w + 6 * MB);     // 2MB
  ushort_t* q2T = (ushort_t*)(w + 8 * MB);     // 2MB
  ushort_t* k2v2T = (ushort_t*)(w + 10 * MB);  // [2048][1024], 4MB
  ushort_t* o2T = (ushort_t*)(w + 14 * MB);    // 2MB
  ushort_t* m1T = (ushort_t*)(w + 16 * MB);    // [4096][1024], 8MB
  ushort_t* m2T = (ushort_t*)(w + 24 * MB);    // [1024][4096], 8MB
  float* bias3 = (float*)(w + 32 * MB);        // 12KB
  float* bias2 = (float*)(w + 32 * MB + 64 * 1024);
  float* pmA = (float*)(w + 32 * MB + 128 * 1024);  // 16KB self pad mask
  float* pmB = (float*)(w + 32 * MB + 160 * 1024);  // 16KB cross pad mask
  ushort_t* xb = (ushort_t*)(w + 33 * MB);     // 8MB; reused later as hlnb
  ushort_t* QKb = (ushort_t*)(w + 41 * MB);    // [4096][2048], 16MB; later Q2b+K2b
  ushort_t* Vt = (ushort_t*)(w + 57 * MB);     // [1024][4096], 8MB (self then cross)
  ushort_t* Ob = (ushort_t*)(w + 65 * MB);     // 8MB
  ushort_t* encb = (ushort_t*)(w + 73 * MB);   // 8MB
  float* xf = (float*)(w + 81 * MB);           // 16MB (post-LN1 x; later r)
  float* hf = (float*)(w + 97 * MB);           // 16MB (x+attn; LN2 in place)
  ushort_t* m1b = (ushort_t*)(w + 113 * MB);   // 32MB
  ushort_t* hlnb = xb;
  ushort_t* Q2b = QKb;                  // [4096][1024]
  ushort_t* K2b = QKb + 4 * MB;         // +8MB bytes -> [4096][1024]

  dim3 B256(256);
  // weight conversions
  P8 p8;
  p8.s[0] = (const float*)d_in[7];  p8.d[0] = qkv1T;
  p8.s[1] = (const float*)d_in[9];  p8.d[1] = qkv1T + 1024 * 1024;
  p8.s[2] = (const float*)d_in[11]; p8.d[2] = qkv1T + 2 * 1024 * 1024;
  p8.s[3] = (const float*)d_in[13]; p8.d[3] = o1T;
  p8.s[4] = (const float*)d_in[17]; p8.d[4] = q2T;
  p8.s[5] = (const float*)d_in[19]; p8.d[5] = k2v2T;
  p8.s[6] = (const float*)d_in[21]; p8.d[6] = k2v2T + 1024 * 1024;
  p8.s[7] = (const float*)d_in[23]; p8.d[7] = o2T;
  wtrans8<<<dim3(32, 32, 8), B256, 0, stream>>>(p8);
  wtrans<<<dim3(128, 32), B256, 0, stream>>>((const float*)d_in[27], m1T, 1024, 4096);
  wtrans<<<dim3(32, 128), B256, 0, stream>>>((const float*)d_in[29], m2T, 4096, 1024);
  f2bcvt<<<4096, B256, 0, stream>>>((const float*)d_in[0], encb);
  bcat<<<12, B256, 0, stream>>>(bias3, (const float*)d_in[8], (const float*)d_in[10],
                                (const float*)d_in[12], 1024, 1024);
  bcat<<<8, B256, 0, stream>>>(bias2, (const float*)d_in[20], (const float*)d_in[22],
                               (const float*)d_in[22], 1024, 1024);
  padmask<<<16, B256, 0, stream>>>((const int*)d_in[2], (const int*)d_in[1], pmA, pmB);

  // embed + LN1
  embed_ln<<<4096, B256, 0, stream>>>((const int*)d_in[2], (const float*)d_in[3],
                                      (const float*)d_in[4], (const float*)d_in[5],
                                      (const float*)d_in[6], xf, xb);
  // fused QKV1 (Q cols scaled, V cols transposed)
  gemm_bt<<<dim3(24, 32), B256, 0, stream>>>(xb, qkv1T, bias3, nullptr, nullptr, QKb, Vt,
                                             4096, 3072, 1024, 0, 1024, 2048);
  attn6<1><<<dim3(16, 16, 2), B256, 0, stream>>>(QKb, 2048, QKb + 1024, 2048, Vt, pmA, Ob);
  gemm_n64<<<dim3(16, 32), B256, 0, stream>>>(Ob, o1T, (const float*)d_in[14], xf, hf, nullptr,
                                              4096, 1024, 1024, 0, 0);
  ln_fwd<<<4096, B256, 0, stream>>>(hf, (const float*)d_in[15], (const float*)d_in[16], hf, hlnb);
  // cross-attn projections
  gemm_n64<<<dim3(16, 32), B256, 0, stream>>>(hlnb, q2T, (const float*)d_in[18], nullptr, nullptr,
                                              Q2b, 4096, 1024, 1024, 0, 1024);
  gemm_bt<<<dim3(16, 32), B256, 0, stream>>>(encb, k2v2T, bias2, nullptr, nullptr, K2b, Vt,
                                             4096, 2048, 1024, 0, 0, 1024);
  attn6<0><<<dim3(16, 16, 2), B256, 0, stream>>>(Q2b, 1024, K2b, 1024, Vt, pmB, Ob);
  gemm_n64<<<dim3(16, 32), B256, 0, stream>>>(Ob, o2T, (const float*)d_in[24], hf, xf, nullptr,
                                              4096, 1024, 1024, 0, 0);
  ln_fwd<<<4096, B256, 0, stream>>>(xf, (const float*)d_in[25], (const float*)d_in[26], nullptr,
                                    hlnb);
  // MLP
  gemm_bt<<<dim3(32, 32), B256, 0, stream>>>(hlnb, m1T, (const float*)d_in[28], nullptr, nullptr,
                                             m1b, nullptr, 4096, 4096, 1024, 1, 0, 4096);
  gemm_n64<<<dim3(16, 32), B256, 0, stream>>>(m1b, m2T, (const float*)d_in[30], xf, (float*)d_out,
                                              nullptr, 4096, 1024, 4096, 0, 0);
}

// Round 6
// 688.392 us; speedup vs baseline: 1.0339x; 1.0004x over previous
//
#include <hip/hip_runtime.h>
#include <hip/hip_bf16.h>

#define S_LEN 2048
#define NEGF -1000000000.0f
#define QSC 0.18033688f  // 0.125 * log2(e)

typedef unsigned short ushort_t;
typedef __attribute__((ext_vector_type(8))) short short8;
typedef __attribute__((ext_vector_type(4))) float f32x4;

#if defined(__has_builtin)
#if __has_builtin(__builtin_amdgcn_exp2f)
#define EXP2 __builtin_amdgcn_exp2f
#endif
#endif
#ifndef EXP2
#define EXP2 exp2f
#endif

__device__ __forceinline__ unsigned short f2b(float f) {
  unsigned int u = __float_as_uint(f);
  return (unsigned short)((u + 0x7fffu + ((u >> 16) & 1u)) >> 16);
}

__device__ __forceinline__ void gld_lds16(const void* g, void* l) {
  __builtin_amdgcn_global_load_lds((__attribute__((address_space(1))) unsigned int*)g,
                                   (__attribute__((address_space(3))) unsigned int*)l, 16, 0, 0);
}

// ---------------- weight transpose f32[K,N] -> bf16[N,K] ----------------
__device__ __forceinline__ void wtrans_body(const float* __restrict__ W,
                                            ushort_t* __restrict__ Wt, int K, int N,
                                            int bx, int by) {
  __shared__ float t[32][33];
  int n0 = bx * 32, k0 = by * 32;
  int tx = threadIdx.x & 31, ty = threadIdx.x >> 5;
#pragma unroll
  for (int i = 0; i < 32; i += 8)
    t[ty + i][tx] = W[(size_t)(k0 + ty + i) * N + n0 + tx];
  __syncthreads();
#pragma unroll
  for (int i = 0; i < 32; i += 8)
    Wt[(size_t)(n0 + ty + i) * K + k0 + tx] = f2b(t[tx][ty + i]);
}

__global__ __launch_bounds__(256) void wtrans(const float* __restrict__ W,
                                              ushort_t* __restrict__ Wt, int K, int N) {
  wtrans_body(W, Wt, K, N, blockIdx.x, blockIdx.y);
}

struct P8 {
  const float* s[8];
  ushort_t* d[8];
};
__global__ __launch_bounds__(256) void wtrans8(P8 p) {
  wtrans_body(p.s[blockIdx.z], p.d[blockIdx.z], 1024, 1024, blockIdx.x, blockIdx.y);
}

__global__ __launch_bounds__(256) void f2bcvt(const float* __restrict__ in,
                                              ushort_t* __restrict__ out) {
  size_t i = ((size_t)blockIdx.x * 256 + threadIdx.x) * 4;
  float4 v = *(const float4*)(in + i);
  union { unsigned short u[4]; uint2 q; } pk;
  pk.u[0] = f2b(v.x); pk.u[1] = f2b(v.y); pk.u[2] = f2b(v.z); pk.u[3] = f2b(v.w);
  *(uint2*)(out + i) = pk.q;
}

__global__ __launch_bounds__(256) void bcat(float* __restrict__ dst, const float* __restrict__ a,
                                            const float* __restrict__ b,
                                            const float* __restrict__ c, int n0, int n1) {
  int i = blockIdx.x * 256 + threadIdx.x;
  float v = (i < n0) ? a[i] : (i < n0 + n1 ? b[i - n0] : c[i - n0 - n1]);
  dst[i] = v;
}

// pad masks -> global f32
__global__ __launch_bounds__(256) void padmask(const int* __restrict__ tids,
                                               const int* __restrict__ iids,
                                               float* __restrict__ pmA,
                                               float* __restrict__ pmB) {
  int i = blockIdx.x * 256 + threadIdx.x;
  pmA[i] = (tids[i] == 0) ? NEGF : 0.0f;
  pmB[i] = (iids[i] == 0) ? NEGF : 0.0f;
}

// ---------------- layernorm ----------------
__device__ __forceinline__ void row_stats(float s, float ss, float* outMean, float* outRstd) {
  __shared__ float red[8];
#pragma unroll
  for (int o = 32; o > 0; o >>= 1) {
    s += __shfl_down(s, o);
    ss += __shfl_down(ss, o);
  }
  int wave = threadIdx.x >> 6, lane = threadIdx.x & 63;
  if (lane == 0) { red[wave] = s; red[4 + wave] = ss; }
  __syncthreads();
  if (threadIdx.x == 0) {
    float S0 = red[0] + red[1] + red[2] + red[3];
    float S1 = red[4] + red[5] + red[6] + red[7];
    float mean = S0 * (1.0f / 1024.0f);
    float var = S1 * (1.0f / 1024.0f) - mean * mean;
    red[0] = mean;
    red[1] = rsqrtf(var + 1e-5f);
  }
  __syncthreads();
  *outMean = red[0];
  *outRstd = red[1];
}

__global__ __launch_bounds__(256) void embed_ln(const int* __restrict__ tids,
                                                const float* __restrict__ tok,
                                                const float* __restrict__ pos,
                                                const float* __restrict__ g,
                                                const float* __restrict__ be,
                                                float* __restrict__ xf,
                                                ushort_t* __restrict__ xb) {
  int row = blockIdx.x;
  int s = row & (S_LEN - 1);
  int id = tids[row];
  int c = threadIdx.x * 4;
  float4 v = *(const float4*)(tok + (size_t)id * 1024 + c);
  float4 p = *(const float4*)(pos + (size_t)s * 1024 + c);
  v.x += p.x; v.y += p.y; v.z += p.z; v.w += p.w;
  float mean, rstd;
  row_stats(v.x + v.y + v.z + v.w, v.x * v.x + v.y * v.y + v.z * v.z + v.w * v.w, &mean, &rstd);
  float4 gv = *(const float4*)(g + c);
  float4 bv = *(const float4*)(be + c);
  float4 o;
  o.x = (v.x - mean) * rstd * gv.x + bv.x;
  o.y = (v.y - mean) * rstd * gv.y + bv.y;
  o.z = (v.z - mean) * rstd * gv.z + bv.z;
  o.w = (v.w - mean) * rstd * gv.w + bv.w;
  *(float4*)(xf + (size_t)row * 1024 + c) = o;
  union { unsigned short u[4]; uint2 q; } pk;
  pk.u[0] = f2b(o.x); pk.u[1] = f2b(o.y); pk.u[2] = f2b(o.z); pk.u[3] = f2b(o.w);
  *(uint2*)(xb + (size_t)row * 1024 + c) = pk.q;
}

__global__ __launch_bounds__(256) void ln_fwd(const float* in, const float* __restrict__ g,
                                              const float* __restrict__ be, float* outF,
                                              ushort_t* __restrict__ outB) {
  int row = blockIdx.x;
  int c = threadIdx.x * 4;
  float4 v = *(const float4*)(in + (size_t)row * 1024 + c);
  float mean, rstd;
  row_stats(v.x + v.y + v.z + v.w, v.x * v.x + v.y * v.y + v.z * v.z + v.w * v.w, &mean, &rstd);
  float4 gv = *(const float4*)(g + c);
  float4 bv = *(const float4*)(be + c);
  float4 o;
  o.x = (v.x - mean) * rstd * gv.x + bv.x;
  o.y = (v.y - mean) * rstd * gv.y + bv.y;
  o.z = (v.z - mean) * rstd * gv.z + bv.z;
  o.w = (v.w - mean) * rstd * gv.w + bv.w;
  if (outF) *(float4*)(outF + (size_t)row * 1024 + c) = o;
  union { unsigned short u[4]; uint2 q; } pk;
  pk.u[0] = f2b(o.x); pk.u[1] = f2b(o.y); pk.u[2] = f2b(o.z); pk.u[3] = f2b(o.w);
  *(uint2*)(outB + (size_t)row * 1024 + c) = pk.q;
}

// ---------------- 128x128 bf16 MFMA GEMM, coalesced LDS-transpose epilogue ----------------
// K-loop unchanged (2-phase, proven 455 TF). Epilogue: stage the 128x128 bf16
// output tile in the (now free) 32KB staging LDS with an XOR chunk swizzle,
// then emit 16B row-major stores (16 lanes = 256B contiguous per row). Fixes
// the 2x write amplification + write-allocate RMW fetch of the old scalar
// (outB) and row-scattered uint2 (outT) stores: WRITE 62->~33MB, FETCH 41->~22MB.
// Tiles are entirely outB (n0+128<=nSplit) or entirely outT (nSplit%128==0).
__global__ __launch_bounds__(256) void gemm_bt(const ushort_t* __restrict__ A,
                                               const ushort_t* __restrict__ Bt,
                                               const float* __restrict__ bias,
                                               ushort_t* __restrict__ outB,
                                               ushort_t* __restrict__ outT,
                                               int M, int N, int K, int act, int scaleN,
                                               int nSplit) {
  __shared__ __align__(16) ushort_t lds[2 * 128 * 64];  // lA | lB, reused as lT
  ushort_t* lA = lds;
  ushort_t* lB = lds + 128 * 64;
  const int tid = threadIdx.x;
  const int wave = tid >> 6, lane = tid & 63;
  const int quad = lane >> 4, l16 = lane & 15;
  const int m0 = blockIdx.y * 128, n0 = blockIdx.x * 128;
  const int wm = (wave >> 1) * 64, wn = (wave & 1) * 64;

  f32x4 zero4 = {0.f, 0.f, 0.f, 0.f};
  f32x4 acc[4][4];
#pragma unroll
  for (int i = 0; i < 4; ++i)
#pragma unroll
    for (int j = 0; j < 4; ++j) acc[i][j] = zero4;

  int rowS[4], chkS[4];
#pragma unroll
  for (int ii = 0; ii < 4; ++ii) {
    int d = (wave * 4 + ii) * 64 + lane;
    rowS[ii] = d >> 3;
    chkS[ii] = (d & 7) ^ (rowS[ii] & 7);
  }

  for (int kt = 0; kt < K; kt += 64) {
    __syncthreads();
#pragma unroll
    for (int ii = 0; ii < 4; ++ii) {
      gld_lds16(A + (size_t)(m0 + rowS[ii]) * K + kt + chkS[ii] * 8,
                (char*)lA + (wave * 4 + ii) * 1024);
      gld_lds16(Bt + (size_t)(n0 + rowS[ii]) * K + kt + chkS[ii] * 8,
                (char*)lB + (wave * 4 + ii) * 1024);
    }
    __syncthreads();
#pragma unroll
    for (int kc = 0; kc < 2; ++kc) {
      short8 af[4], bf[4];
#pragma unroll
      for (int mt = 0; mt < 4; ++mt) {
        int r = wm + mt * 16 + l16;
        int c = (kc * 4 + quad) ^ (r & 7);
        af[mt] = *(const short8*)(lA + r * 64 + c * 8);
      }
#pragma unroll
      for (int nt = 0; nt < 4; ++nt) {
        int r = wn + nt * 16 + l16;
        int c = (kc * 4 + quad) ^ (r & 7);
        bf[nt] = *(const short8*)(lB + r * 64 + c * 8);
      }
#pragma unroll
      for (int mt = 0; mt < 4; ++mt)
#pragma unroll
        for (int nt = 0; nt < 4; ++nt)
          acc[mt][nt] = __builtin_amdgcn_mfma_f32_16x16x32_bf16(af[mt], bf[nt], acc[mt][nt], 0, 0, 0);
    }
  }

  // ---- epilogue: LDS transpose + coalesced 16B stores ----
  __syncthreads();  // all waves done reading lA/lB
  ushort_t* lT = lds;  // 128 rows x 128 ushorts (32KB), chunk-XOR swizzled
  const bool interior = (n0 + 128 <= nSplit);

  if (interior) {
    // layout [m local][n local]
#pragma unroll
    for (int nt = 0; nt < 4; ++nt) {
      int gn = n0 + wn + nt * 16 + l16;
      float bv = bias[gn];
      const bool sc = gn < scaleN;
      const int colL = wn + nt * 16 + l16;
#pragma unroll
      for (int mt = 0; mt < 4; ++mt) {
        int rb = wm + mt * 16 + quad * 4;
#pragma unroll
        for (int reg = 0; reg < 4; ++reg) {
          float v = acc[mt][nt][reg] + bv;
          if (act == 1) v = 0.5f * v * (1.0f + erff(v * 0.70710678118654752f));
          if (sc) v *= QSC;
          int r = rb + reg;
          lT[r * 128 + (((colL >> 3) ^ (r & 7)) << 3) + (colL & 7)] = f2b(v);
        }
      }
    }
    __syncthreads();
#pragma unroll
    for (int rr = 0; rr < 8; ++rr) {
      int r = rr * 16 + (tid >> 4);
      int c = tid & 15;
      const uint4 vv = *(const uint4*)(lT + r * 128 + ((c ^ (r & 7)) << 3));
      *(uint4*)(outB + (size_t)(m0 + r) * nSplit + n0 + c * 8) = vv;
    }
  } else {
    // layout [n local][m local] -> transposed store to outT[n][m]
#pragma unroll
    for (int nt = 0; nt < 4; ++nt) {
      int gn = n0 + wn + nt * 16 + l16;
      float bv = bias[gn];
      const int rn = wn + nt * 16 + l16;  // local n row in lT
#pragma unroll
      for (int mt = 0; mt < 4; ++mt) {
        int cb = wm + mt * 16 + quad * 4;
#pragma unroll
        for (int reg = 0; reg < 4; ++reg) {
          int cm = cb + reg;  // local m col
          lT[rn * 128 + (((cm >> 3) ^ (rn & 7)) << 3) + (cm & 7)] = f2b(acc[mt][nt][reg] + bv);
        }
      }
    }
    __syncthreads();
#pragma unroll
    for (int rr = 0; rr < 8; ++rr) {
      int r = rr * 16 + (tid >> 4);  // local n
      int c = tid & 15;
      const uint4 vv = *(const uint4*)(lT + r * 128 + ((c ^ (r & 7)) << 3));
      *(uint4*)(outT + (size_t)(n0 - nSplit + r) * M + m0 + c * 8) = vv;
    }
  }
}

// ---------------- 128x64 tile GEMM (single-buffer, round-0 proven) ----------------
__global__ __launch_bounds__(256) void gemm_n64(const ushort_t* __restrict__ A,
                                                const ushort_t* __restrict__ Bt,
                                                const float* __restrict__ bias,
                                                const float* __restrict__ res,
                                                float* __restrict__ outF,
                                                ushort_t* __restrict__ outB,
                                                int M, int N, int K, int act, int scaleN) {
  __shared__ __align__(16) ushort_t lA[128 * 64];
  __shared__ __align__(16) ushort_t lB[64 * 64];
  const int tid = threadIdx.x;
  const int wave = tid >> 6, lane = tid & 63;
  const int quad = lane >> 4, l16 = lane & 15;
  const int m0 = blockIdx.y * 128, n0 = blockIdx.x * 64;
  const int wm = wave * 32;

  f32x4 zero4 = {0.f, 0.f, 0.f, 0.f};
  f32x4 acc[2][4];
#pragma unroll
  for (int i = 0; i < 2; ++i)
#pragma unroll
    for (int j = 0; j < 4; ++j) acc[i][j] = zero4;

  int rowA[4], chkA[4], rowB[2], chkB[2];
#pragma unroll
  for (int ii = 0; ii < 4; ++ii) {
    int d = (wave * 4 + ii) * 64 + lane;
    rowA[ii] = d >> 3;
    chkA[ii] = (d & 7) ^ (rowA[ii] & 7);
  }
#pragma unroll
  for (int ii = 0; ii < 2; ++ii) {
    int d = (wave * 2 + ii) * 64 + lane;
    rowB[ii] = d >> 3;
    chkB[ii] = (d & 7) ^ (rowB[ii] & 7);
  }

  for (int kt = 0; kt < K; kt += 64) {
    __syncthreads();
#pragma unroll
    for (int ii = 0; ii < 4; ++ii)
      gld_lds16(A + (size_t)(m0 + rowA[ii]) * K + kt + chkA[ii] * 8,
                (char*)lA + (wave * 4 + ii) * 1024);
#pragma unroll
    for (int ii = 0; ii < 2; ++ii)
      gld_lds16(Bt + (size_t)(n0 + rowB[ii]) * K + kt + chkB[ii] * 8,
                (char*)lB + (wave * 2 + ii) * 1024);
    __syncthreads();
#pragma unroll
    for (int kc = 0; kc < 2; ++kc) {
      short8 af[2], bf[4];
#pragma unroll
      for (int mt = 0; mt < 2; ++mt) {
        int r = wm + mt * 16 + l16;
        int c = (kc * 4 + quad) ^ (r & 7);
        af[mt] = *(const short8*)(lA + r * 64 + c * 8);
      }
#pragma unroll
      for (int nt = 0; nt < 4; ++nt) {
        int r = nt * 16 + l16;
        int c = (kc * 4 + quad) ^ (r & 7);
        bf[nt] = *(const short8*)(lB + r * 64 + c * 8);
      }
#pragma unroll
      for (int mt = 0; mt < 2; ++mt)
#pragma unroll
        for (int nt = 0; nt < 4; ++nt)
          acc[mt][nt] = __builtin_amdgcn_mfma_f32_16x16x32_bf16(af[mt], bf[nt], acc[mt][nt], 0, 0, 0);
    }
  }

#pragma unroll
  for (int nt = 0; nt < 4; ++nt) {
    int gn = n0 + nt * 16 + l16;
    float bv = bias[gn];
#pragma unroll
    for (int mt = 0; mt < 2; ++mt) {
      int gmb = m0 + wm + mt * 16 + quad * 4;
#pragma unroll
      for (int reg = 0; reg < 4; ++reg) {
        size_t idx = (size_t)(gmb + reg) * N + gn;
        float v = acc[mt][nt][reg] + bv;
        if (act == 1) v = 0.5f * v * (1.0f + erff(v * 0.70710678118654752f));
        if (gn < scaleN) v *= QSC;
        if (res) v += res[idx];
        if (outF) outF[idx] = v;
        if (outB) outB[idx] = f2b(v);
      }
    }
  }
}

// ---------------- flash attention v6: work-balanced q-tile pairing ----------------
template <int CAUSAL>
__global__ __launch_bounds__(256, 2) void attn6(const ushort_t* __restrict__ Qp, int ldQ,
                                                const ushort_t* __restrict__ Kp, int ldK,
                                                const ushort_t* __restrict__ Vt,
                                                const float* __restrict__ pmg,
                                                ushort_t* __restrict__ O) {
  __shared__ __align__(16) ushort_t lK[2][64 * 64];
  __shared__ __align__(16) ushort_t lV[2][64 * 64];
  __shared__ __align__(16) ushort_t lP[4][16 * 64];

  const int h = blockIdx.y, b = blockIdx.z;
  const int bx = blockIdx.x;
  const int gq[2] = {CAUSAL ? (31 - bx) : (2 * bx), CAUSAL ? bx : (2 * bx + 1)};
  const int tid = threadIdx.x;
  const int wave = tid >> 6, lane = tid & 63;
  const int quad = lane >> 4, l16 = lane & 15;
  const float* pmb = pmg + b * S_LEN;

  short8 qf[2][2];
#pragma unroll
  for (int s = 0; s < 2; ++s) {
    const ushort_t* qb =
        Qp + ((size_t)(b * S_LEN) + gq[s] * 64 + wave * 16 + l16) * ldQ + h * 64;
    qf[s][0] = *(const short8*)(qb + quad * 8);
    qf[s][1] = *(const short8*)(qb + 32 + quad * 8);
  }

  f32x4 zero4 = {0.f, 0.f, 0.f, 0.f};
  f32x4 acc_o[2][4];
  float lsum[2][4];
#pragma unroll
  for (int s = 0; s < 2; ++s)
#pragma unroll
    for (int nt = 0; nt < 4; ++nt) {
      acc_o[s][nt] = zero4;
      lsum[s][nt] = 0.f;
    }

  const int nkv = CAUSAL ? (gq[0] + 1) : (S_LEN / 64);

  int srow[2], scs[2];
#pragma unroll
  for (int ii = 0; ii < 2; ++ii) {
    int slot = (wave * 2 + ii) * 64 + lane;
    srow[ii] = slot >> 3;
    scs[ii] = ((slot & 7) ^ (srow[ii] & 7)) * 8;
  }

#define STAGE_KV(KV0, BUF)                                                            \
  do {                                                                                \
    _Pragma("unroll") for (int ii = 0; ii < 2; ++ii) {                                \
      gld_lds16(Kp + (size_t)(b * S_LEN + (KV0) + srow[ii]) * ldK + h * 64 + scs[ii], \
                (char*)lK[BUF] + (wave * 2 + ii) * 1024);                             \
      gld_lds16(Vt + (size_t)(h * 64 + srow[ii]) * 4096 + b * S_LEN + (KV0) + scs[ii],\
                (char*)lV[BUF] + (wave * 2 + ii) * 1024);                             \
    }                                                                                 \
  } while (0)

  STAGE_KV(0, 0);
  __syncthreads();

  int cur = 0;
  for (int kv = 0; kv < nkv; ++kv) {
    const int kv0 = kv * 64;
    if (kv + 1 < nkv) STAGE_KV(kv0 + 64, cur ^ 1);

    float pmv[4];
#pragma unroll
    for (int nt = 0; nt < 4; ++nt) pmv[nt] = pmb[kv0 + nt * 16 + l16];

    const ushort_t* cK = lK[cur];
    const ushort_t* cV = lV[cur];

    // fragments shared by both q sub-tiles
    short8 kf[2][4], vf[2][4];
#pragma unroll
    for (int kc = 0; kc < 2; ++kc)
#pragma unroll
      for (int nt = 0; nt < 4; ++nt) {
        int r = nt * 16 + l16;
        int c = (kc * 4 + quad) ^ (r & 7);
        kf[kc][nt] = *(const short8*)(cK + r * 64 + c * 8);
        vf[kc][nt] = *(const short8*)(cV + r * 64 + c * 8);
      }

#pragma unroll
    for (int s = 0; s < 2; ++s) {
      if (CAUSAL && kv > gq[s]) continue;  // fully masked sub-tile (uniform branch)

      f32x4 sacc[4];
#pragma unroll
      for (int nt = 0; nt < 4; ++nt) sacc[nt] = zero4;
#pragma unroll
      for (int kc = 0; kc < 2; ++kc)
#pragma unroll
        for (int nt = 0; nt < 4; ++nt)
          sacc[nt] = __builtin_amdgcn_mfma_f32_16x16x32_bf16(qf[s][kc], kf[kc][nt], sacc[nt], 0, 0, 0);

      const int qbase = gq[s] * 64 + wave * 16 + quad * 4;
      const bool diag = CAUSAL && (kv == gq[s]);
#pragma unroll
      for (int nt = 0; nt < 4; ++nt) {
        int kk = kv0 + nt * 16 + l16;
#pragma unroll
        for (int reg = 0; reg < 4; ++reg) {
          float sv = sacc[nt][reg] + pmv[nt];
          if (diag && kk > qbase + reg) sv = NEGF;
          float p = EXP2(sv);
          lsum[s][reg] += p;
          int q = quad * 4 + reg;
          int cc = (nt * 2 + (l16 >> 3)) ^ (q & 7);
          lP[wave][q * 64 + cc * 8 + (l16 & 7)] = f2b(p);
        }
      }

#pragma unroll
      for (int kc = 0; kc < 2; ++kc) {
        int cp = (kc * 4 + quad) ^ (l16 & 7);
        short8 pf = *(const short8*)(&lP[wave][l16 * 64 + cp * 8]);
#pragma unroll
        for (int nt = 0; nt < 4; ++nt)
          acc_o[s][nt] = __builtin_amdgcn_mfma_f32_16x16x32_bf16(pf, vf[kc][nt], acc_o[s][nt], 0, 0, 0);
      }
    }
    __syncthreads();
    cur ^= 1;
  }  // kv
#undef STAGE_KV

#pragma unroll
  for (int s = 0; s < 2; ++s) {
    float inv[4];
#pragma unroll
    for (int reg = 0; reg < 4; ++reg) {
      float t = lsum[s][reg];
      t += __shfl_xor(t, 1);
      t += __shfl_xor(t, 2);
      t += __shfl_xor(t, 4);
      t += __shfl_xor(t, 8);
      inv[reg] = 1.0f / t;
    }
#pragma unroll
    for (int nt = 0; nt < 4; ++nt)
#pragma unroll
      for (int reg = 0; reg < 4; ++reg) {
        int qr = gq[s] * 64 + wave * 16 + quad * 4 + reg;
        O[((size_t)(b * S_LEN) + qr) * 1024 + h * 64 + nt * 16 + l16] =
            f2b(acc_o[s][nt][reg] * inv[reg]);
      }
  }
}

// ---------------- launch ----------------
extern "C" void kernel_launch(void* const* d_in, const int* in_sizes, int n_in,
                              void* d_out, int out_size, void* d_ws, size_t ws_size,
                              hipStream_t stream) {
  (void)in_sizes; (void)n_in; (void)out_size; (void)ws_size;
  const size_t MB = 1024 * 1024;
  char* w = (char*)d_ws;
  ushort_t* qkv1T = (ushort_t*)(w + 0);        // [3072][1024] bf16, 6MB
  ushort_t* o1T = (ushort_t*)(w + 6 * MB);     // 2MB
  ushort_t* q2T = (ushort_t*)(w + 8 * MB);     // 2MB
  ushort_t* k2v2T = (ushort_t*)(w + 10 * MB);  // [2048][1024], 4MB
  ushort_t* o2T = (ushort_t*)(w + 14 * MB);    // 2MB
  ushort_t* m1T = (ushort_t*)(w + 16 * MB);    // [4096][1024], 8MB
  ushort_t* m2T = (ushort_t*)(w + 24 * MB);    // [1024][4096], 8MB
  float* bias3 = (float*)(w + 32 * MB);        // 12KB
  float* bias2 = (float*)(w + 32 * MB + 64 * 1024);
  float* pmA = (float*)(w + 32 * MB + 128 * 1024);  // 16KB self pad mask
  float* pmB = (float*)(w + 32 * MB + 160 * 1024);  // 16KB cross pad mask
  ushort_t* xb = (ushort_t*)(w + 33 * MB);     // 8MB; reused later as hlnb
  ushort_t* QKb = (ushort_t*)(w + 41 * MB);    // [4096][2048], 16MB; later Q2b+K2b
  ushort_t* Vt = (ushort_t*)(w + 57 * MB);     // [1024][4096], 8MB (self then cross)
  ushort_t* Ob = (ushort_t*)(w + 65 * MB);     // 8MB
  ushort_t* encb = (ushort_t*)(w + 73 * MB);   // 8MB
  float* xf = (float*)(w + 81 * MB);           // 16MB (post-LN1 x; later r)
  float* hf = (float*)(w + 97 * MB);           // 16MB (x+attn; LN2 in place)
  ushort_t* m1b = (ushort_t*)(w + 113 * MB);   // 32MB
  ushort_t* hlnb = xb;
  ushort_t* Q2b = QKb;                  // [4096][1024]
  ushort_t* K2b = QKb + 4 * MB;         // +8MB bytes -> [4096][1024]

  dim3 B256(256);
  // weight conversions
  P8 p8;
  p8.s[0] = (const float*)d_in[7];  p8.d[0] = qkv1T;
  p8.s[1] = (const float*)d_in[9];  p8.d[1] = qkv1T + 1024 * 1024;
  p8.s[2] = (const float*)d_in[11]; p8.d[2] = qkv1T + 2 * 1024 * 1024;
  p8.s[3] = (const float*)d_in[13]; p8.d[3] = o1T;
  p8.s[4] = (const float*)d_in[17]; p8.d[4] = q2T;
  p8.s[5] = (const float*)d_in[19]; p8.d[5] = k2v2T;
  p8.s[6] = (const float*)d_in[21]; p8.d[6] = k2v2T + 1024 * 1024;
  p8.s[7] = (const float*)d_in[23]; p8.d[7] = o2T;
  wtrans8<<<dim3(32, 32, 8), B256, 0, stream>>>(p8);
  wtrans<<<dim3(128, 32), B256, 0, stream>>>((const float*)d_in[27], m1T, 1024, 4096);
  wtrans<<<dim3(32, 128), B256, 0, stream>>>((const float*)d_in[29], m2T, 4096, 1024);
  f2bcvt<<<4096, B256, 0, stream>>>((const float*)d_in[0], encb);
  bcat<<<12, B256, 0, stream>>>(bias3, (const float*)d_in[8], (const float*)d_in[10],
                                (const float*)d_in[12], 1024, 1024);
  bcat<<<8, B256, 0, stream>>>(bias2, (const float*)d_in[20], (const float*)d_in[22],
                               (const float*)d_in[22], 1024, 1024);
  padmask<<<16, B256, 0, stream>>>((const int*)d_in[2], (const int*)d_in[1], pmA, pmB);

  // embed + LN1
  embed_ln<<<4096, B256, 0, stream>>>((const int*)d_in[2], (const float*)d_in[3],
                                      (const float*)d_in[4], (const float*)d_in[5],
                                      (const float*)d_in[6], xf, xb);
  // fused QKV1 (Q cols scaled, V cols transposed)
  gemm_bt<<<dim3(24, 32), B256, 0, stream>>>(xb, qkv1T, bias3, QKb, Vt,
                                             4096, 3072, 1024, 0, 1024, 2048);
  attn6<1><<<dim3(16, 16, 2), B256, 0, stream>>>(QKb, 2048, QKb + 1024, 2048, Vt, pmA, Ob);
  gemm_n64<<<dim3(16, 32), B256, 0, stream>>>(Ob, o1T, (const float*)d_in[14], xf, hf, nullptr,
                                              4096, 1024, 1024, 0, 0);
  ln_fwd<<<4096, B256, 0, stream>>>(hf, (const float*)d_in[15], (const float*)d_in[16], hf, hlnb);
  // cross-attn projections
  gemm_n64<<<dim3(16, 32), B256, 0, stream>>>(hlnb, q2T, (const float*)d_in[18], nullptr, nullptr,
                                              Q2b, 4096, 1024, 1024, 0, 1024);
  gemm_bt<<<dim3(16, 32), B256, 0, stream>>>(encb, k2v2T, bias2, K2b, Vt,
                                             4096, 2048, 1024, 0, 0, 1024);
  attn6<0><<<dim3(16, 16, 2), B256, 0, stream>>>(Q2b, 1024, K2b, 1024, Vt, pmB, Ob);
  gemm_n64<<<dim3(16, 32), B256, 0, stream>>>(Ob, o2T, (const float*)d_in[24], hf, xf, nullptr,
                                              4096, 1024, 1024, 0, 0);
  ln_fwd<<<4096, B256, 0, stream>>>(xf, (const float*)d_in[25], (const float*)d_in[26], nullptr,
                                    hlnb);
  // MLP
  gemm_bt<<<dim3(32, 32), B256, 0, stream>>>(hlnb, m1T, (const float*)d_in[28], m1b, nullptr,
                                             4096, 4096, 1024, 1, 0, 4096);
  gemm_n64<<<dim3(16, 32), B256, 0, stream>>>(m1b, m2T, (const float*)d_in[30], xf, (float*)d_out,
                                              nullptr, 4096, 1024, 4096, 0, 0);
}